// Round 9
// baseline (222.605 us; speedup 1.0000x reference)
//
#include <hip/hip_runtime.h>
#include <hip/hip_bf16.h>
#include <hip/hip_fp16.h>

// GraphSAGE fwd, round 9.
// lin0 folded into conv1 (U1=W0@W1l, U2=W0@W1r, c1=b0@(W1l+W1r)+b1l).
// Bucket build -> counting sort ONCE (baggr32s writes gns/gorder CSR).
// conv1 lin + p2=h1@W2l + q2=h1@W2r fused in one MFMA kernel (h1 in LDS only).
// conv2 aggregation = pure gather kernel (uint4 rows, 16 rows in flight/wave),
// fused lin2+head epilogue -> gs/gd; h2/ag2 never materialized.

#define IN_X 32
#define IN_E 64
#define HID 128
#define OUTF 64

#define BSHIFT 7
#define BSZ 128          // nodes per bucket
#define NBP 1024         // padded bucket count
#define CHUNK 4096       // edges per histogram/scatter block
#define CAP 4096         // max edges per bucket in LDS (mean 2560)

typedef _Float16 f16x8 __attribute__((ext_vector_type(8)));
typedef float f32x4 __attribute__((ext_vector_type(4)));

__device__ __forceinline__ float2 h2f2(uint v) {
  __half2 h = *reinterpret_cast<__half2*>(&v);
  return __half22float2(h);
}

// ---------- prep + x->fp16: blocks 0..64 = weight prep, rest = tohalf ----------
__global__ __launch_bounds__(256) void k_prep(
    const float* __restrict__ W0, const float* __restrict__ b0,
    const float* __restrict__ W1l, const float* __restrict__ b1l,
    const float* __restrict__ W1r,
    const float* __restrict__ W2l, const float* __restrict__ W2r,
    __half* __restrict__ U1T, __half* __restrict__ U2T, float* __restrict__ c1,
    __half* __restrict__ W2lT, __half* __restrict__ W2rT,
    const float* __restrict__ x, __half* __restrict__ xh, int xtotal) {
  __shared__ float sW0[IN_X * IN_E];
  const int blk = blockIdx.x;
  if (blk < 32) {
    for (int t = threadIdx.x; t < IN_X * IN_E; t += 256) sW0[t] = W0[t];
    __syncthreads();
    const int o = blk * 256 + threadIdx.x;
    const int hf = o >> 12;
    const int rem = o & 4095;
    const int j = rem >> 5, i = rem & 31;
    const float* W = hf ? W1r : W1l;
    float u = 0.f;
    #pragma unroll 8
    for (int k = 0; k < IN_E; ++k) u += sW0[i * IN_E + k] * W[k * HID + j];
    (hf ? U2T : U1T)[j * IN_X + i] = __float2half(u);
  } else if (blk == 32) {
    const int j = threadIdx.x;
    if (j < HID) {
      float cv = b1l[j];
      for (int k = 0; k < IN_E; ++k)
        cv += b0[k] * (W1l[k * HID + j] + W1r[k * HID + j]);
      c1[j] = cv;
    }
  } else if (blk < 65) {
    int i = (blk - 33) * 256 + threadIdx.x;   // over HID*OUTF = 8192
    if (i < HID * OUTF) {
      int k = i >> 6, c = i & 63;
      W2lT[c * HID + k] = __float2half(W2l[i]);
      W2rT[c * HID + k] = __float2half(W2r[i]);
    }
  } else {
    int i = ((blk - 65) * 256 + threadIdx.x) * 8;
    if (i < xtotal) {
      float4 a = *(const float4*)(x + i);
      float4 b = *(const float4*)(x + i + 4);
      __half2 h0 = __floats2half2_rn(a.x, a.y);
      __half2 h1 = __floats2half2_rn(a.z, a.w);
      __half2 h2 = __floats2half2_rn(b.x, b.y);
      __half2 h3 = __floats2half2_rn(b.z, b.w);
      uint4 o = { *(uint*)&h0, *(uint*)&h1, *(uint*)&h2, *(uint*)&h3 };
      *(uint4*)(xh + i) = o;
    }
  }
}

// ---------- bucket histogram per chunk ----------
__global__ __launch_bounds__(512) void k_bcount(const int* __restrict__ dst,
    int* __restrict__ counts, int E, int nchunk) {
  __shared__ int hist[NBP];
  const int cblk = blockIdx.x;
  for (int i = threadIdx.x; i < NBP; i += 512) hist[i] = 0;
  __syncthreads();
  const int base = cblk * CHUNK;
  int d[CHUNK / 512];
  #pragma unroll
  for (int k = 0; k < CHUNK / 512; ++k) {
    int e = base + k * 512 + threadIdx.x;
    d[k] = (e < E) ? dst[e] : -1;
  }
  #pragma unroll
  for (int k = 0; k < CHUNK / 512; ++k)
    if (d[k] >= 0) atomicAdd(&hist[d[k] >> BSHIFT], 1);
  __syncthreads();
  for (int i = threadIdx.x; i < NBP; i += 512)
    counts[(size_t)i * nchunk + cblk] = hist[i];
}

// ---------- per-bucket exclusive scan over chunks ----------
__global__ __launch_bounds__(256) void k_bscan(int* __restrict__ counts,
    int* __restrict__ bucketTotal, int nchunk) {
  const int b = blockIdx.x;
  int* row = counts + (size_t)b * nchunk;
  __shared__ int wsum[4];
  __shared__ int carry_s;
  const int tid = threadIdx.x, lane = tid & 63, wid = tid >> 6;
  if (tid == 0) carry_s = 0;
  __syncthreads();
  for (int base = 0; base < nchunk; base += 256) {
    int i = base + tid;
    int v = (i < nchunk) ? row[i] : 0;
    int x = v;
    #pragma unroll
    for (int s = 1; s < 64; s <<= 1) {
      int y = __shfl_up(x, s, 64);
      if (lane >= s) x += y;
    }
    if (lane == 63) wsum[wid] = x;
    __syncthreads();
    int waveoff = 0;
    #pragma unroll
    for (int w = 0; w < 4; ++w) if (w < wid) waveoff += wsum[w];
    const int carry = carry_s;
    if (i < nchunk) row[i] = carry + waveoff + (x - v);
    __syncthreads();
    if (tid == 0) carry_s = carry + wsum[0] + wsum[1] + wsum[2] + wsum[3];
    __syncthreads();
  }
  if (tid == 0) bucketTotal[b] = carry_s;
}

// ---------- scan over bucket totals ----------
__global__ __launch_bounds__(1024) void k_bscan2(const int* __restrict__ bucketTotal,
    int* __restrict__ bucketBase) {
  __shared__ int wsum[16];
  const int tid = threadIdx.x, lane = tid & 63, wid = tid >> 6;
  int v = (tid < NBP) ? bucketTotal[tid] : 0;
  int x = v;
  #pragma unroll
  for (int s = 1; s < 64; s <<= 1) {
    int y = __shfl_up(x, s, 64);
    if (lane >= s) x += y;
  }
  if (lane == 63) wsum[wid] = x;
  __syncthreads();
  int waveoff = 0;
  #pragma unroll
  for (int w = 0; w < 16; ++w) if (w < wid) waveoff += wsum[w];
  bucketBase[tid] = waveoff + (x - v);
  if (tid == NBP - 1) bucketBase[NBP] = waveoff + x;
}

// ---------- scatter packed edges into bucket regions ----------
__global__ __launch_bounds__(512) void k_bscatter(const int* __restrict__ src,
    const int* __restrict__ dst, const int* __restrict__ counts,
    const int* __restrict__ bucketBase, uint* __restrict__ bucketData,
    int E, int nchunk) {
  __shared__ int hist[NBP];
  const int cblk = blockIdx.x;
  for (int i = threadIdx.x; i < NBP; i += 512)
    hist[i] = bucketBase[i] + counts[(size_t)i * nchunk + cblk];
  __syncthreads();
  const int base = cblk * CHUNK;
  int d[CHUNK / 512], s[CHUNK / 512];
  #pragma unroll
  for (int k = 0; k < CHUNK / 512; ++k) {
    int e = base + k * 512 + threadIdx.x;
    d[k] = (e < E) ? dst[e] : -1;
    s[k] = (e < E) ? src[e] : 0;
  }
  #pragma unroll
  for (int k = 0; k < CHUNK / 512; ++k) {
    if (d[k] >= 0) {
      int pos = atomicAdd(&hist[d[k] >> BSHIFT], 1);
      bucketData[pos] = ((uint)s[k] << BSHIFT) | (uint)(d[k] & (BSZ - 1));
    }
  }
}

// ---------- conv1 aggregation + CSR export ----------
// Counting sort per bucket, gather-sum xh (row = 64B = 4 lanes x uint4,
// 16 rows per load inst, x2 unroll = 32 rows in flight), CSR export.
__global__ __launch_bounds__(512) void k_baggr32s(const __half* __restrict__ feat,
    const uint* __restrict__ bucketData, const int* __restrict__ bucketBase,
    __half* __restrict__ aggr, uint* __restrict__ gorder, int* __restrict__ gns,
    int N, int E) {
  __shared__ int nodeStart[BSZ + 1];
  __shared__ int cursor[BSZ];
  __shared__ int order[CAP];
  const int b = blockIdx.x;
  const int tid = threadIdx.x;
  const int lane = tid & 63, wid = tid >> 6;
  const int e0 = bucketBase[b], e1 = bucketBase[b + 1];

  if (tid < BSZ) cursor[tid] = 0;
  __syncthreads();
  for (int i = e0 + tid; i < e1; i += 512)
    atomicAdd(&cursor[bucketData[i] & (BSZ - 1)], 1);
  __syncthreads();

  if (wid == 0) {
    int v0 = cursor[lane], v1 = cursor[64 + lane];
    int x0 = v0, x1 = v1;
    #pragma unroll
    for (int s = 1; s < 64; s <<= 1) {
      int y0 = __shfl_up(x0, s, 64);
      int y1 = __shfl_up(x1, s, 64);
      if (lane >= s) { x0 += y0; x1 += y1; }
    }
    int tot0 = __shfl(x0, 63, 64);
    nodeStart[lane] = x0 - v0;
    nodeStart[64 + lane] = tot0 + x1 - v1;
    if (lane == 63) nodeStart[BSZ] = tot0 + x1;
  }
  __syncthreads();
  if (tid < BSZ) cursor[tid] = nodeStart[tid];
  __syncthreads();

  for (int i = e0 + tid; i < e1; i += 512) {
    uint p = bucketData[i];
    int pos = atomicAdd(&cursor[p & (BSZ - 1)], 1);
    if (pos < CAP) order[pos] = (int)(p >> BSHIFT);
  }
  __syncthreads();

  // export CSR
  {
    const int cnt = min(e1 - e0, CAP);
    for (int i = tid; i < cnt; i += 512) gorder[e0 + i] = (uint)order[i];
    if (tid < BSZ) {
      const int n = b * BSZ + tid;
      if (n < N) gns[n] = e0 + min(nodeStart[tid], CAP);
    }
    if (b == 0 && tid == 0) gns[N] = E;
  }

  // gather-sum xh: g = row-in-group (0..15), e = uint4 index (0..3)
  const int nodes = min(BSZ, N - b * BSZ);
  const int g = lane >> 2, e = lane & 3;
  for (int n = wid; n < nodes; n += 8) {
    const int s = min(nodeStart[n], CAP), t = min(nodeStart[n + 1], CAP);
    float4 accA = {0.f, 0.f, 0.f, 0.f}, accB = {0.f, 0.f, 0.f, 0.f};
    int j = s;
    for (; j + 32 <= t; j += 32) {
      int r0 = order[j + g], r1 = order[j + 16 + g];
      uint4 v0 = ((const uint4*)(feat + (size_t)r0 * IN_X))[e];
      uint4 v1 = ((const uint4*)(feat + (size_t)r1 * IN_X))[e];
      float2 p0 = h2f2(v0.x), p1 = h2f2(v0.y), p2_ = h2f2(v0.z), p3 = h2f2(v0.w);
      float2 q0 = h2f2(v1.x), q1 = h2f2(v1.y), q2_ = h2f2(v1.z), q3 = h2f2(v1.w);
      accA.x += p0.x + q0.x; accA.y += p0.y + q0.y;
      accA.z += p1.x + q1.x; accA.w += p1.y + q1.y;
      accB.x += p2_.x + q2_.x; accB.y += p2_.y + q2_.y;
      accB.z += p3.x + q3.x; accB.w += p3.y + q3.y;
    }
    for (; j < t; j += 16) {
      if (j + g < t) {
        int r = order[j + g];
        uint4 v = ((const uint4*)(feat + (size_t)r * IN_X))[e];
        float2 p0 = h2f2(v.x), p1 = h2f2(v.y), p2_ = h2f2(v.z), p3 = h2f2(v.w);
        accA.x += p0.x; accA.y += p0.y; accA.z += p1.x; accA.w += p1.y;
        accB.x += p2_.x; accB.y += p2_.y; accB.z += p3.x; accB.w += p3.y;
      }
    }
    #pragma unroll
    for (int m = 4; m < 64; m <<= 1) {
      accA.x += __shfl_xor(accA.x, m, 64); accA.y += __shfl_xor(accA.y, m, 64);
      accA.z += __shfl_xor(accA.z, m, 64); accA.w += __shfl_xor(accA.w, m, 64);
      accB.x += __shfl_xor(accB.x, m, 64); accB.y += __shfl_xor(accB.y, m, 64);
      accB.z += __shfl_xor(accB.z, m, 64); accB.w += __shfl_xor(accB.w, m, 64);
    }
    if (g == 0) {
      float inv = 1.f / fmaxf((float)(nodeStart[n + 1] - nodeStart[n]), 1.f);
      __half2 o0 = __floats2half2_rn(accA.x * inv, accA.y * inv);
      __half2 o1 = __floats2half2_rn(accA.z * inv, accA.w * inv);
      __half2 o2 = __floats2half2_rn(accB.x * inv, accB.y * inv);
      __half2 o3 = __floats2half2_rn(accB.z * inv, accB.w * inv);
      uint4 o = { *(uint*)&o0, *(uint*)&o1, *(uint*)&o2, *(uint*)&o3 };
      ((uint4*)(aggr + ((size_t)(b * BSZ + n)) * IN_X))[e] = o;
    }
  }
}

// ---------- fused conv1 lin + p2/q2 ----------
__global__ __launch_bounds__(256) void k_conv1fused(
    const __half* __restrict__ axm, const __half* __restrict__ xh,
    const __half* __restrict__ U1T, const __half* __restrict__ U2T,
    const float* __restrict__ c1,
    const __half* __restrict__ W2lT, const __half* __restrict__ W2rT,
    __half* __restrict__ p2, __half* __restrict__ q2, int N) {
  __shared__ _Float16 tile[4][16 * HID];
  const int lane = threadIdx.x & 63;
  const int wid = threadIdx.x >> 6;
  const int row0 = blockIdx.x * 64 + wid * 16;
  const int lr = lane & 15;
  const int lk = (lane >> 4) * 8;

  {
    f16x8 b1[8], b2[8];
    #pragma unroll
    for (int ct = 0; ct < 8; ++ct) {
      const int c = ct * 16 + lr;
      b1[ct] = *(const f16x8*)((const _Float16*)U1T + (size_t)c * IN_X + lk);
      b2[ct] = *(const f16x8*)((const _Float16*)U2T + (size_t)c * IN_X + lk);
    }
    f32x4 acc[8];
    #pragma unroll
    for (int ct = 0; ct < 8; ++ct) {
      float bv = c1[ct * 16 + lr];
      acc[ct] = (f32x4){bv, bv, bv, bv};
    }
    const int rA = min(row0 + lr, N - 1);
    f16x8 a1 = *(const f16x8*)((const _Float16*)axm + (size_t)rA * IN_X + lk);
    f16x8 a2 = *(const f16x8*)((const _Float16*)xh + (size_t)rA * IN_X + lk);
    #pragma unroll
    for (int ct = 0; ct < 8; ++ct)
      acc[ct] = __builtin_amdgcn_mfma_f32_16x16x32_f16(a1, b1[ct], acc[ct], 0, 0, 0);
    #pragma unroll
    for (int ct = 0; ct < 8; ++ct)
      acc[ct] = __builtin_amdgcn_mfma_f32_16x16x32_f16(a2, b2[ct], acc[ct], 0, 0, 0);
    #pragma unroll
    for (int ct = 0; ct < 8; ++ct) {
      #pragma unroll
      for (int r = 0; r < 4; ++r) {
        const int row = (lane >> 4) * 4 + r;
        const int col = ct * 16 + lr;
        int idx = (row * HID + col) ^ ((row & 7) << 3);
        tile[wid][idx] = (_Float16)fmaxf(acc[ct][r], 0.f);
      }
    }
  }
  __syncthreads();

  f16x8 a[4];
  #pragma unroll
  for (int t = 0; t < 4; ++t) {
    int idx = (lr * HID + t * 32 + lk) ^ ((lr & 7) << 3);
    a[t] = *(const f16x8*)&tile[wid][idx];
  }
  f16x8 wl[4][4], wr[4][4];
  #pragma unroll
  for (int t = 0; t < 4; ++t)
    #pragma unroll
    for (int ct = 0; ct < 4; ++ct) {
      const int c = ct * 16 + lr;
      wl[t][ct] = *(const f16x8*)((const _Float16*)W2lT + (size_t)c * HID + t * 32 + lk);
      wr[t][ct] = *(const f16x8*)((const _Float16*)W2rT + (size_t)c * HID + t * 32 + lk);
    }
  f32x4 accp[4] = {}, accq[4] = {};
  #pragma unroll
  for (int t = 0; t < 4; ++t) {
    #pragma unroll
    for (int ct = 0; ct < 4; ++ct)
      accp[ct] = __builtin_amdgcn_mfma_f32_16x16x32_f16(a[t], wl[t][ct], accp[ct], 0, 0, 0);
    #pragma unroll
    for (int ct = 0; ct < 4; ++ct)
      accq[ct] = __builtin_amdgcn_mfma_f32_16x16x32_f16(a[t], wr[t][ct], accq[ct], 0, 0, 0);
  }
  #pragma unroll
  for (int ct = 0; ct < 4; ++ct) {
    const int c = ct * 16 + lr;
    #pragma unroll
    for (int r = 0; r < 4; ++r) {
      const int row = row0 + (lane >> 4) * 4 + r;
      if (row < N) {
        p2[(size_t)row * OUTF + c] = __float2half(accp[ct][r]);
        q2[(size_t)row * OUTF + c] = __float2half(accq[ct][r]);
      }
    }
  }
}

// ---------- conv2 gather + fused lin2/head ----------
// One wave per node. Row = 128B = 8 lanes x uint4; 8 rows per load inst,
// x2 unroll = 16 rows in flight. h2 in registers; gs/gd out.
__global__ __launch_bounds__(512) void k_gaggr64(const __half* __restrict__ p2,
    const int* __restrict__ gns, const uint* __restrict__ gorder,
    const __half* __restrict__ q2, const float* __restrict__ b2l,
    const float* __restrict__ Wp, float* __restrict__ gs, float* __restrict__ gd,
    int N) {
  const int lane = threadIdx.x & 63;
  const int gwave = (blockIdx.x * 512 + threadIdx.x) >> 6;
  const int nwaves = (gridDim.x * 512) >> 6;
  const int g = lane >> 3, e = lane & 7;   // 8 lanes x uint4 = 128B row
  const float4 bl0 = ((const float4*)b2l)[2 * e];
  const float4 bl1 = ((const float4*)b2l)[2 * e + 1];
  const float4 ws0 = ((const float4*)Wp)[2 * e];
  const float4 ws1 = ((const float4*)Wp)[2 * e + 1];
  const float4 wd0 = ((const float4*)(Wp + OUTF))[2 * e];
  const float4 wd1 = ((const float4*)(Wp + OUTF))[2 * e + 1];
  for (int n = gwave; n < N; n += nwaves) {
    const int s = gns[n], t = gns[n + 1];
    float4 accA = {0.f, 0.f, 0.f, 0.f}, accB = {0.f, 0.f, 0.f, 0.f};
    int j = s;
    for (; j + 16 <= t; j += 16) {
      int r0 = (int)gorder[j + g], r1 = (int)gorder[j + 8 + g];
      uint4 v0 = ((const uint4*)(p2 + (size_t)r0 * OUTF))[e];
      uint4 v1 = ((const uint4*)(p2 + (size_t)r1 * OUTF))[e];
      float2 p0 = h2f2(v0.x), p1 = h2f2(v0.y), p2_ = h2f2(v0.z), p3 = h2f2(v0.w);
      float2 q0 = h2f2(v1.x), q1 = h2f2(v1.y), q2_ = h2f2(v1.z), q3 = h2f2(v1.w);
      accA.x += p0.x + q0.x; accA.y += p0.y + q0.y;
      accA.z += p1.x + q1.x; accA.w += p1.y + q1.y;
      accB.x += p2_.x + q2_.x; accB.y += p2_.y + q2_.y;
      accB.z += p3.x + q3.x; accB.w += p3.y + q3.y;
    }
    for (; j < t; j += 8) {
      if (j + g < t) {
        int r = (int)gorder[j + g];
        uint4 v = ((const uint4*)(p2 + (size_t)r * OUTF))[e];
        float2 p0 = h2f2(v.x), p1 = h2f2(v.y), p2_ = h2f2(v.z), p3 = h2f2(v.w);
        accA.x += p0.x; accA.y += p0.y; accA.z += p1.x; accA.w += p1.y;
        accB.x += p2_.x; accB.y += p2_.y; accB.z += p3.x; accB.w += p3.y;
      }
    }
    #pragma unroll
    for (int m = 8; m < 64; m <<= 1) {
      accA.x += __shfl_xor(accA.x, m, 64); accA.y += __shfl_xor(accA.y, m, 64);
      accA.z += __shfl_xor(accA.z, m, 64); accA.w += __shfl_xor(accA.w, m, 64);
      accB.x += __shfl_xor(accB.x, m, 64); accB.y += __shfl_xor(accB.y, m, 64);
      accB.z += __shfl_xor(accB.z, m, 64); accB.w += __shfl_xor(accB.w, m, 64);
    }
    const float inv = 1.f / fmaxf((float)(t - s), 1.f);
    uint4 qv = ((const uint4*)(q2 + (size_t)n * OUTF))[e];
    float2 qa = h2f2(qv.x), qb = h2f2(qv.y), qc = h2f2(qv.z), qd = h2f2(qv.w);
    float h0v = qa.x + accA.x * inv + bl0.x;
    float h1v = qa.y + accA.y * inv + bl0.y;
    float h2v = qb.x + accA.z * inv + bl0.z;
    float h3v = qb.y + accA.w * inv + bl0.w;
    float h4v = qc.x + accB.x * inv + bl1.x;
    float h5v = qc.y + accB.y * inv + bl1.y;
    float h6v = qd.x + accB.z * inv + bl1.z;
    float h7v = qd.y + accB.w * inv + bl1.w;
    float sp = h0v * ws0.x + h1v * ws0.y + h2v * ws0.z + h3v * ws0.w
             + h4v * ws1.x + h5v * ws1.y + h6v * ws1.z + h7v * ws1.w;
    float dp = h0v * wd0.x + h1v * wd0.y + h2v * wd0.z + h3v * wd0.w
             + h4v * wd1.x + h5v * wd1.y + h6v * wd1.z + h7v * wd1.w;
    #pragma unroll
    for (int m = 1; m < 8; m <<= 1) {
      sp += __shfl_xor(sp, m, 64);
      dp += __shfl_xor(dp, m, 64);
    }
    if (lane == 0) { gs[n] = sp; gd[n] = dp; }
  }
}

// ---------- per-edge: raw = gs[src] + gd[dst] + bp; sigmoid ----------
__global__ __launch_bounds__(256) void k_edge(const float* __restrict__ gs,
    const float* __restrict__ gd, const int* __restrict__ srcI,
    const int* __restrict__ dstI, const float* __restrict__ bp,
    float* __restrict__ out, int E) {
  int e = blockIdx.x * 256 + threadIdx.x;
  if (e >= E) return;
  float raw = gs[srcI[e]] + gd[dstI[e]] + bp[0];
  out[e] = raw;
  out[(size_t)E + e] = 1.f / (1.f + expf(-raw));
}

extern "C" void kernel_launch(void* const* d_in, const int* in_sizes, int n_in,
                              void* d_out, int out_size, void* d_ws, size_t ws_size,
                              hipStream_t stream) {
  const float* x   = (const float*)d_in[0];
  const int*   ei  = (const int*)d_in[1];
  const float* W0  = (const float*)d_in[2];
  const float* b0  = (const float*)d_in[3];
  const float* W1l = (const float*)d_in[4];
  const float* b1l = (const float*)d_in[5];
  const float* W1r = (const float*)d_in[6];
  const float* W2l = (const float*)d_in[7];
  const float* b2l = (const float*)d_in[8];
  const float* W2r = (const float*)d_in[9];
  const float* Wp  = (const float*)d_in[10];
  const float* bp  = (const float*)d_in[11];

  const int N = in_sizes[0] / IN_X;
  const int E = in_sizes[1] / 2;
  const int* srcI = ei;
  const int* dstI = ei + E;
  float* out = (float*)d_out;

  const int NB = (N + BSZ - 1) >> BSHIFT;
  const int nchunk = (E + CHUNK - 1) / CHUNK;

  // workspace layout
  __half* xh  = (__half*)d_ws;                   // [N][32]
  __half* axm = xh + (size_t)N * IN_X;           // [N][32]
  __half* p2  = axm + (size_t)N * IN_X;          // [N][64]
  __half* q2  = p2 + (size_t)N * OUTF;           // [N][64]
  float* gs   = (float*)(q2 + (size_t)N * OUTF);
  float* gd   = gs + N;
  uintptr_t wp = ((uintptr_t)(gd + N) + 15) & ~(uintptr_t)15;
  __half* U1T  = (__half*)wp;                    // [128][32]
  __half* U2T  = U1T + HID * IN_X;
  __half* W2lT = U2T + HID * IN_X;               // [64][128]
  __half* W2rT = W2lT + OUTF * HID;
  float* c1    = (float*)(W2rT + OUTF * HID);    // [128]
  int* counts      = (int*)(c1 + HID);           // [NBP][nchunk]
  int* bucketTotal = counts + (size_t)NBP * nchunk;
  int* bucketBase  = bucketTotal + NBP;          // [NBP+1]
  uint* bucketData = (uint*)(bucketBase + NBP + 1);  // [E]
  int* gns     = (int*)(bucketData + E);         // [N+1]
  uint* gorder = (uint*)(gns + N + 1);           // [E]

  const int xblocks = (N * IN_X / 8 + 255) / 256;
  k_prep<<<65 + xblocks, 256, 0, stream>>>(W0, b0, W1l, b1l, W1r, W2l, W2r,
                                           U1T, U2T, c1, W2lT, W2rT,
                                           x, xh, N * IN_X);
  // bucket build
  k_bcount<<<nchunk, 512, 0, stream>>>(dstI, counts, E, nchunk);
  k_bscan<<<NBP, 256, 0, stream>>>(counts, bucketTotal, nchunk);
  k_bscan2<<<1, 1024, 0, stream>>>(bucketTotal, bucketBase);
  k_bscatter<<<nchunk, 512, 0, stream>>>(srcI, dstI, counts, bucketBase, bucketData, E, nchunk);
  // conv1: axm = mean(xh_j), export CSR (gns/gorder)
  k_baggr32s<<<NB, 512, 0, stream>>>(xh, bucketData, bucketBase, axm, gorder, gns, N, E);
  // fused conv1 lin + p2/q2
  k_conv1fused<<<(N + 63) / 64, 256, 0, stream>>>(axm, xh, U1T, U2T, c1,
                                                  W2lT, W2rT, p2, q2, N);
  // conv2 gather + fused lin2/head
  k_gaggr64<<<1024, 512, 0, stream>>>(p2, gns, gorder, q2, b2l, Wp, gs, gd, N);
  // edge head
  k_edge<<<(E + 255) / 256, 256, 0, stream>>>(gs, gd, srcI, dstI, bp, out, E);
}

// Round 10
// 179.819 us; speedup vs baseline: 1.2379x; 1.2379x over previous
//
#include <hip/hip_runtime.h>
#include <hip/hip_bf16.h>
#include <hip/hip_fp16.h>

// GraphSAGE fwd, round 10.
// lin0 folded into conv1 (U1=W0@W1l, U2=W0@W1r, c1=b0@(W1l+W1r)+b1l).
// ONE fused bucket-build kernel: per-chunk LDS histogram -> global atomic
// range-reserve -> scatter into fixed-capacity buckets (b*CAP base).
// Counting sort ONCE in baggr32s (exports gapped CSR gns/gne/gorder).
// conv1 lin + p2/q2 fused MFMA kernel (h1 in LDS only).
// conv2 = pure uint2 gather (8B/lane — uint4 regressed, R9) + fused lin2/head.

#define IN_X 32
#define IN_E 64
#define HID 128
#define OUTF 64

#define BSHIFT 7
#define BSZ 128          // nodes per bucket
#define NBP 1024         // padded bucket count
#define CHUNK 4096       // edges per scatter block
#define CAP 4096         // slots per bucket (mean 2560, +30 sigma)

typedef _Float16 f16x8 __attribute__((ext_vector_type(8)));
typedef float f32x4 __attribute__((ext_vector_type(4)));

__device__ __forceinline__ float2 h2f2(uint v) {
  __half2 h = *reinterpret_cast<__half2*>(&v);
  return __half22float2(h);
}

// ---------- prep + x->fp16: blocks 0..64 = weight prep, rest = tohalf ----------
__global__ __launch_bounds__(256) void k_prep(
    const float* __restrict__ W0, const float* __restrict__ b0,
    const float* __restrict__ W1l, const float* __restrict__ b1l,
    const float* __restrict__ W1r,
    const float* __restrict__ W2l, const float* __restrict__ W2r,
    __half* __restrict__ U1T, __half* __restrict__ U2T, float* __restrict__ c1,
    __half* __restrict__ W2lT, __half* __restrict__ W2rT,
    const float* __restrict__ x, __half* __restrict__ xh, int xtotal) {
  __shared__ float sW0[IN_X * IN_E];
  const int blk = blockIdx.x;
  if (blk < 32) {
    for (int t = threadIdx.x; t < IN_X * IN_E; t += 256) sW0[t] = W0[t];
    __syncthreads();
    const int o = blk * 256 + threadIdx.x;
    const int hf = o >> 12;
    const int rem = o & 4095;
    const int j = rem >> 5, i = rem & 31;
    const float* W = hf ? W1r : W1l;
    float u = 0.f;
    #pragma unroll 8
    for (int k = 0; k < IN_E; ++k) u += sW0[i * IN_E + k] * W[k * HID + j];
    (hf ? U2T : U1T)[j * IN_X + i] = __float2half(u);
  } else if (blk == 32) {
    const int j = threadIdx.x;
    if (j < HID) {
      float cv = b1l[j];
      for (int k = 0; k < IN_E; ++k)
        cv += b0[k] * (W1l[k * HID + j] + W1r[k * HID + j]);
      c1[j] = cv;
    }
  } else if (blk < 65) {
    int i = (blk - 33) * 256 + threadIdx.x;   // over HID*OUTF = 8192
    if (i < HID * OUTF) {
      int k = i >> 6, c = i & 63;
      W2lT[c * HID + k] = __float2half(W2l[i]);
      W2rT[c * HID + k] = __float2half(W2r[i]);
    }
  } else {
    int i = ((blk - 65) * 256 + threadIdx.x) * 8;
    if (i < xtotal) {
      float4 a = *(const float4*)(x + i);
      float4 b = *(const float4*)(x + i + 4);
      __half2 h0 = __floats2half2_rn(a.x, a.y);
      __half2 h1 = __floats2half2_rn(a.z, a.w);
      __half2 h2 = __floats2half2_rn(b.x, b.y);
      __half2 h3 = __floats2half2_rn(b.z, b.w);
      uint4 o = { *(uint*)&h0, *(uint*)&h1, *(uint*)&h2, *(uint*)&h3 };
      *(uint4*)(xh + i) = o;
    }
  }
}

// ---------- fused bucket build: hist -> global reserve -> scatter ----------
__global__ __launch_bounds__(512) void k_scatfuse(const int* __restrict__ src,
    const int* __restrict__ dst, int* __restrict__ gcursor,
    uint* __restrict__ bucketData, int E) {
  __shared__ int hist[NBP];
  const int cblk = blockIdx.x;
  for (int i = threadIdx.x; i < NBP; i += 512) hist[i] = 0;
  __syncthreads();
  const int base = cblk * CHUNK;
  int d[CHUNK / 512], s[CHUNK / 512];
  #pragma unroll
  for (int k = 0; k < CHUNK / 512; ++k) {
    int e = base + k * 512 + threadIdx.x;
    d[k] = (e < E) ? dst[e] : -1;
    s[k] = (e < E) ? src[e] : 0;
  }
  #pragma unroll
  for (int k = 0; k < CHUNK / 512; ++k)
    if (d[k] >= 0) atomicAdd(&hist[d[k] >> BSHIFT], 1);
  __syncthreads();
  // reserve a global range per bucket; hist[i] becomes this chunk's cursor
  for (int i = threadIdx.x; i < NBP; i += 512) {
    int h = hist[i];
    hist[i] = (h > 0) ? atomicAdd(&gcursor[i], h) : 0;
  }
  __syncthreads();
  #pragma unroll
  for (int k = 0; k < CHUNK / 512; ++k) {
    if (d[k] >= 0) {
      int bkt = d[k] >> BSHIFT;
      int pos = atomicAdd(&hist[bkt], 1);
      if (pos < CAP)
        bucketData[(size_t)bkt * CAP + pos] =
            ((uint)s[k] << BSHIFT) | (uint)(d[k] & (BSZ - 1));
    }
  }
}

// ---------- conv1 aggregation + gapped-CSR export ----------
// Counting sort per bucket, gather-sum xh (64B row = 8 lanes x uint2,
// 8 rows/load inst, x2 unroll), export gorder + gns/gne.
__global__ __launch_bounds__(512) void k_baggr32s(const __half* __restrict__ feat,
    const uint* __restrict__ bucketData, const int* __restrict__ gcnt,
    __half* __restrict__ aggr, uint* __restrict__ gorder,
    int* __restrict__ gns, int* __restrict__ gne, int N) {
  constexpr int FW = IN_X;     // 32 halves per row
  constexpr int LPR = FW / 4;  // 8 lanes per row (uint2 each)
  constexpr int RPW = 64 / LPR;
  __shared__ int nodeStart[BSZ + 1];
  __shared__ int cursor[BSZ];
  __shared__ int order[CAP];
  const int b = blockIdx.x;
  const int tid = threadIdx.x;
  const int lane = tid & 63, wid = tid >> 6;
  const int e0 = b * CAP;
  const int cnt = min(gcnt[b], CAP);

  if (tid < BSZ) cursor[tid] = 0;
  __syncthreads();
  for (int i = tid; i < cnt; i += 512)
    atomicAdd(&cursor[bucketData[e0 + i] & (BSZ - 1)], 1);
  __syncthreads();

  if (wid == 0) {
    int v0 = cursor[lane], v1 = cursor[64 + lane];
    int x0 = v0, x1 = v1;
    #pragma unroll
    for (int s = 1; s < 64; s <<= 1) {
      int y0 = __shfl_up(x0, s, 64);
      int y1 = __shfl_up(x1, s, 64);
      if (lane >= s) { x0 += y0; x1 += y1; }
    }
    int tot0 = __shfl(x0, 63, 64);
    nodeStart[lane] = x0 - v0;
    nodeStart[64 + lane] = tot0 + x1 - v1;
    if (lane == 63) nodeStart[BSZ] = tot0 + x1;
  }
  __syncthreads();
  if (tid < BSZ) cursor[tid] = nodeStart[tid];
  __syncthreads();

  for (int i = tid; i < cnt; i += 512) {
    uint p = bucketData[e0 + i];
    int pos = atomicAdd(&cursor[p & (BSZ - 1)], 1);
    order[pos] = (int)(p >> BSHIFT);
  }
  __syncthreads();

  // export gapped CSR
  for (int i = tid; i < cnt; i += 512) gorder[e0 + i] = (uint)order[i];
  if (tid < BSZ) {
    const int n = b * BSZ + tid;
    if (n < N) { gns[n] = e0 + nodeStart[tid]; gne[n] = e0 + nodeStart[tid + 1]; }
  }

  // gather-sum xh
  const int nodes = min(BSZ, N - b * BSZ);
  const int g = lane / LPR, e = lane % LPR;
  for (int n = wid; n < nodes; n += 8) {
    const int s = nodeStart[n], t = nodeStart[n + 1];
    float4 acc = {0.f, 0.f, 0.f, 0.f};
    int j = s;
    for (; j + 2 * RPW <= t; j += 2 * RPW) {
      int r0 = order[j + g], r1 = order[j + RPW + g];
      uint2 v0 = ((const uint2*)(feat + (size_t)r0 * FW))[e];
      uint2 v1 = ((const uint2*)(feat + (size_t)r1 * FW))[e];
      float2 a0 = h2f2(v0.x), b0_ = h2f2(v0.y);
      float2 a1 = h2f2(v1.x), b1_ = h2f2(v1.y);
      acc.x += a0.x + a1.x; acc.y += a0.y + a1.y;
      acc.z += b0_.x + b1_.x; acc.w += b0_.y + b1_.y;
    }
    for (; j < t; j += RPW) {
      if (j + g < t) {
        int r = order[j + g];
        uint2 v = ((const uint2*)(feat + (size_t)r * FW))[e];
        float2 a = h2f2(v.x), bb = h2f2(v.y);
        acc.x += a.x; acc.y += a.y; acc.z += bb.x; acc.w += bb.y;
      }
    }
    #pragma unroll
    for (int m = LPR; m < 64; m <<= 1) {
      acc.x += __shfl_xor(acc.x, m, 64);
      acc.y += __shfl_xor(acc.y, m, 64);
      acc.z += __shfl_xor(acc.z, m, 64);
      acc.w += __shfl_xor(acc.w, m, 64);
    }
    if (g == 0) {
      float inv = 1.f / fmaxf((float)(t - s), 1.f);
      __half2 o0 = __floats2half2_rn(acc.x * inv, acc.y * inv);
      __half2 o1 = __floats2half2_rn(acc.z * inv, acc.w * inv);
      uint2 o = { *(uint*)&o0, *(uint*)&o1 };
      ((uint2*)(aggr + ((size_t)(b * BSZ + n)) * FW))[e] = o;
    }
  }
}

// ---------- fused conv1 lin + p2/q2 ----------
__global__ __launch_bounds__(256) void k_conv1fused(
    const __half* __restrict__ axm, const __half* __restrict__ xh,
    const __half* __restrict__ U1T, const __half* __restrict__ U2T,
    const float* __restrict__ c1,
    const __half* __restrict__ W2lT, const __half* __restrict__ W2rT,
    __half* __restrict__ p2, __half* __restrict__ q2, int N) {
  __shared__ _Float16 tile[4][16 * HID];
  const int lane = threadIdx.x & 63;
  const int wid = threadIdx.x >> 6;
  const int row0 = blockIdx.x * 64 + wid * 16;
  const int lr = lane & 15;
  const int lk = (lane >> 4) * 8;

  {
    f16x8 b1[8], b2[8];
    #pragma unroll
    for (int ct = 0; ct < 8; ++ct) {
      const int c = ct * 16 + lr;
      b1[ct] = *(const f16x8*)((const _Float16*)U1T + (size_t)c * IN_X + lk);
      b2[ct] = *(const f16x8*)((const _Float16*)U2T + (size_t)c * IN_X + lk);
    }
    f32x4 acc[8];
    #pragma unroll
    for (int ct = 0; ct < 8; ++ct) {
      float bv = c1[ct * 16 + lr];
      acc[ct] = (f32x4){bv, bv, bv, bv};
    }
    const int rA = min(row0 + lr, N - 1);
    f16x8 a1 = *(const f16x8*)((const _Float16*)axm + (size_t)rA * IN_X + lk);
    f16x8 a2 = *(const f16x8*)((const _Float16*)xh + (size_t)rA * IN_X + lk);
    #pragma unroll
    for (int ct = 0; ct < 8; ++ct)
      acc[ct] = __builtin_amdgcn_mfma_f32_16x16x32_f16(a1, b1[ct], acc[ct], 0, 0, 0);
    #pragma unroll
    for (int ct = 0; ct < 8; ++ct)
      acc[ct] = __builtin_amdgcn_mfma_f32_16x16x32_f16(a2, b2[ct], acc[ct], 0, 0, 0);
    #pragma unroll
    for (int ct = 0; ct < 8; ++ct) {
      #pragma unroll
      for (int r = 0; r < 4; ++r) {
        const int row = (lane >> 4) * 4 + r;
        const int col = ct * 16 + lr;
        int idx = (row * HID + col) ^ ((row & 7) << 3);
        tile[wid][idx] = (_Float16)fmaxf(acc[ct][r], 0.f);
      }
    }
  }
  __syncthreads();

  f16x8 a[4];
  #pragma unroll
  for (int t = 0; t < 4; ++t) {
    int idx = (lr * HID + t * 32 + lk) ^ ((lr & 7) << 3);
    a[t] = *(const f16x8*)&tile[wid][idx];
  }
  f16x8 wl[4][4], wr[4][4];
  #pragma unroll
  for (int t = 0; t < 4; ++t)
    #pragma unroll
    for (int ct = 0; ct < 4; ++ct) {
      const int c = ct * 16 + lr;
      wl[t][ct] = *(const f16x8*)((const _Float16*)W2lT + (size_t)c * HID + t * 32 + lk);
      wr[t][ct] = *(const f16x8*)((const _Float16*)W2rT + (size_t)c * HID + t * 32 + lk);
    }
  f32x4 accp[4] = {}, accq[4] = {};
  #pragma unroll
  for (int t = 0; t < 4; ++t) {
    #pragma unroll
    for (int ct = 0; ct < 4; ++ct)
      accp[ct] = __builtin_amdgcn_mfma_f32_16x16x32_f16(a[t], wl[t][ct], accp[ct], 0, 0, 0);
    #pragma unroll
    for (int ct = 0; ct < 4; ++ct)
      accq[ct] = __builtin_amdgcn_mfma_f32_16x16x32_f16(a[t], wr[t][ct], accq[ct], 0, 0, 0);
  }
  #pragma unroll
  for (int ct = 0; ct < 4; ++ct) {
    const int c = ct * 16 + lr;
    #pragma unroll
    for (int r = 0; r < 4; ++r) {
      const int row = row0 + (lane >> 4) * 4 + r;
      if (row < N) {
        p2[(size_t)row * OUTF + c] = __float2half(accp[ct][r]);
        q2[(size_t)row * OUTF + c] = __float2half(accq[ct][r]);
      }
    }
  }
}

// ---------- conv2 gather + fused lin2/head (uint2, 16 lanes/row) ----------
__global__ __launch_bounds__(512) void k_gaggr64(const __half* __restrict__ p2,
    const int* __restrict__ gns, const int* __restrict__ gne,
    const uint* __restrict__ gorder,
    const __half* __restrict__ q2, const float* __restrict__ b2l,
    const float* __restrict__ Wp, float* __restrict__ gs, float* __restrict__ gd,
    int N) {
  const int lane = threadIdx.x & 63;
  const int gwave = (blockIdx.x * 512 + threadIdx.x) >> 6;
  const int nwaves = (gridDim.x * 512) >> 6;
  const int g = lane >> 4, e = lane & 15;   // 16 lanes x uint2 = 128B row
  const float4 bl  = ((const float4*)b2l)[e];
  const float4 ws4 = ((const float4*)Wp)[e];
  const float4 wd4 = ((const float4*)(Wp + OUTF))[e];
  for (int n = gwave; n < N; n += nwaves) {
    const int s = gns[n], t = gne[n];
    float4 acc = {0.f, 0.f, 0.f, 0.f};
    int j = s;
    for (; j + 8 <= t; j += 8) {
      int r0 = (int)gorder[j + g], r1 = (int)gorder[j + 4 + g];
      uint2 v0 = ((const uint2*)(p2 + (size_t)r0 * OUTF))[e];
      uint2 v1 = ((const uint2*)(p2 + (size_t)r1 * OUTF))[e];
      float2 a0 = h2f2(v0.x), b0_ = h2f2(v0.y);
      float2 a1 = h2f2(v1.x), b1_ = h2f2(v1.y);
      acc.x += a0.x + a1.x; acc.y += a0.y + a1.y;
      acc.z += b0_.x + b1_.x; acc.w += b0_.y + b1_.y;
    }
    for (; j < t; j += 4) {
      if (j + g < t) {
        int r = (int)gorder[j + g];
        uint2 v = ((const uint2*)(p2 + (size_t)r * OUTF))[e];
        float2 a0 = h2f2(v.x), b0_ = h2f2(v.y);
        acc.x += a0.x; acc.y += a0.y; acc.z += b0_.x; acc.w += b0_.y;
      }
    }
    acc.x += __shfl_xor(acc.x, 16, 64); acc.y += __shfl_xor(acc.y, 16, 64);
    acc.z += __shfl_xor(acc.z, 16, 64); acc.w += __shfl_xor(acc.w, 16, 64);
    acc.x += __shfl_xor(acc.x, 32, 64); acc.y += __shfl_xor(acc.y, 32, 64);
    acc.z += __shfl_xor(acc.z, 32, 64); acc.w += __shfl_xor(acc.w, 32, 64);
    const float inv = 1.f / fmaxf((float)(t - s), 1.f);
    uint2 qv = ((const uint2*)(q2 + (size_t)n * OUTF))[e];
    float2 qa = h2f2(qv.x), qb = h2f2(qv.y);
    float h0v = qa.x + acc.x * inv + bl.x;
    float h1v = qa.y + acc.y * inv + bl.y;
    float h2v = qb.x + acc.z * inv + bl.z;
    float h3v = qb.y + acc.w * inv + bl.w;
    float sp = h0v * ws4.x + h1v * ws4.y + h2v * ws4.z + h3v * ws4.w;
    float dp = h0v * wd4.x + h1v * wd4.y + h2v * wd4.z + h3v * wd4.w;
    #pragma unroll
    for (int m = 1; m < 16; m <<= 1) {
      sp += __shfl_xor(sp, m, 64);
      dp += __shfl_xor(dp, m, 64);
    }
    if (lane == 0) { gs[n] = sp; gd[n] = dp; }
  }
}

// ---------- per-edge: raw = gs[src] + gd[dst] + bp; sigmoid ----------
__global__ __launch_bounds__(256) void k_edge(const float* __restrict__ gs,
    const float* __restrict__ gd, const int* __restrict__ srcI,
    const int* __restrict__ dstI, const float* __restrict__ bp,
    float* __restrict__ out, int E) {
  int e = blockIdx.x * 256 + threadIdx.x;
  if (e >= E) return;
  float raw = gs[srcI[e]] + gd[dstI[e]] + bp[0];
  out[e] = raw;
  out[(size_t)E + e] = 1.f / (1.f + expf(-raw));
}

extern "C" void kernel_launch(void* const* d_in, const int* in_sizes, int n_in,
                              void* d_out, int out_size, void* d_ws, size_t ws_size,
                              hipStream_t stream) {
  const float* x   = (const float*)d_in[0];
  const int*   ei  = (const int*)d_in[1];
  const float* W0  = (const float*)d_in[2];
  const float* b0  = (const float*)d_in[3];
  const float* W1l = (const float*)d_in[4];
  const float* b1l = (const float*)d_in[5];
  const float* W1r = (const float*)d_in[6];
  const float* W2l = (const float*)d_in[7];
  const float* b2l = (const float*)d_in[8];
  const float* W2r = (const float*)d_in[9];
  const float* Wp  = (const float*)d_in[10];
  const float* bp  = (const float*)d_in[11];

  const int N = in_sizes[0] / IN_X;
  const int E = in_sizes[1] / 2;
  const int* srcI = ei;
  const int* dstI = ei + E;
  float* out = (float*)d_out;

  const int NB = (N + BSZ - 1) >> BSHIFT;
  const int nchunk = (E + CHUNK - 1) / CHUNK;

  // workspace layout
  __half* xh  = (__half*)d_ws;                   // [N][32]
  __half* axm = xh + (size_t)N * IN_X;           // [N][32]
  __half* p2  = axm + (size_t)N * IN_X;          // [N][64]
  __half* q2  = p2 + (size_t)N * OUTF;           // [N][64]
  float* gs   = (float*)(q2 + (size_t)N * OUTF);
  float* gd   = gs + N;
  uintptr_t wp = ((uintptr_t)(gd + N) + 15) & ~(uintptr_t)15;
  __half* U1T  = (__half*)wp;                    // [128][32]
  __half* U2T  = U1T + HID * IN_X;
  __half* W2lT = U2T + HID * IN_X;               // [64][128]
  __half* W2rT = W2lT + OUTF * HID;
  float* c1    = (float*)(W2rT + OUTF * HID);    // [128]
  int* gcursor = (int*)(c1 + HID);               // [NBP]
  int* gns     = gcursor + NBP;                  // [N+1]
  int* gne     = gns + N + 1;                    // [N]
  uint* bucketData = (uint*)(gne + N);           // [NBP*CAP]
  uint* gorder     = bucketData + (size_t)NBP * CAP;  // [NBP*CAP]

  hipMemsetAsync(gcursor, 0, sizeof(int) * NBP, stream);

  const int xblocks = (N * IN_X / 8 + 255) / 256;
  k_prep<<<65 + xblocks, 256, 0, stream>>>(W0, b0, W1l, b1l, W1r, W2l, W2r,
                                           U1T, U2T, c1, W2lT, W2rT,
                                           x, xh, N * IN_X);
  // fused bucket build
  k_scatfuse<<<nchunk, 512, 0, stream>>>(srcI, dstI, gcursor, bucketData, E);
  // conv1: axm = mean(xh_j), counting sort + gapped CSR export
  k_baggr32s<<<NB, 512, 0, stream>>>(xh, bucketData, gcursor, axm, gorder, gns, gne, N);
  // fused conv1 lin + p2/q2
  k_conv1fused<<<(N + 63) / 64, 256, 0, stream>>>(axm, xh, U1T, U2T, c1,
                                                  W2lT, W2rT, p2, q2, N);
  // conv2 gather + fused lin2/head
  k_gaggr64<<<1024, 512, 0, stream>>>(p2, gns, gne, gorder, q2, b2l, Wp, gs, gd, N);
  // edge head
  k_edge<<<(E + 255) / 256, 256, 0, stream>>>(gs, gd, srcI, dstI, bp, out, E);
}

// Round 11
// 176.126 us; speedup vs baseline: 1.2639x; 1.0210x over previous
//
#include <hip/hip_runtime.h>
#include <hip/hip_bf16.h>
#include <hip/hip_fp16.h>

// GraphSAGE fwd, round 11.
// lin0 folded into conv1 (U1=W0@W1l, U2=W0@W1r, c1=b0@(W1l+W1r)+b1l).
// ONE fused bucket-build kernel (hist -> global range-reserve -> scatter,
// fixed-capacity buckets). Counting sort ONCE (gapped CSR gns/gne/gorder).
// conv1 lin + p2/q2 fused MFMA kernel (h1 in LDS only).
// conv2 = pure uint2 gather + fused lin2/head. Gathers accumulate in PACKED
// FP16 (v_pk_add_f16) — 4x less VALU than cvt-to-f32 — with 16 rows in
// flight per wave (R10: VALUBusy 42% co-limited the latency-bound gather).

#define IN_X 32
#define IN_E 64
#define HID 128
#define OUTF 64

#define BSHIFT 7
#define BSZ 128          // nodes per bucket
#define NBP 1024         // padded bucket count
#define CHUNK 4096       // edges per scatter block
#define CAP 4096         // slots per bucket (mean 2560, +30 sigma)

typedef _Float16 f16x8 __attribute__((ext_vector_type(8)));
typedef float f32x4 __attribute__((ext_vector_type(4)));

__device__ __forceinline__ float2 h2f2(uint v) {
  __half2 h = *reinterpret_cast<__half2*>(&v);
  return __half22float2(h);
}
__device__ __forceinline__ __half2 u2h(uint v) {
  return *reinterpret_cast<__half2*>(&v);
}

// ---------- prep + x->fp16: blocks 0..64 = weight prep, rest = tohalf ----------
__global__ __launch_bounds__(256) void k_prep(
    const float* __restrict__ W0, const float* __restrict__ b0,
    const float* __restrict__ W1l, const float* __restrict__ b1l,
    const float* __restrict__ W1r,
    const float* __restrict__ W2l, const float* __restrict__ W2r,
    __half* __restrict__ U1T, __half* __restrict__ U2T, float* __restrict__ c1,
    __half* __restrict__ W2lT, __half* __restrict__ W2rT,
    const float* __restrict__ x, __half* __restrict__ xh, int xtotal) {
  __shared__ float sW0[IN_X * IN_E];
  const int blk = blockIdx.x;
  if (blk < 32) {
    for (int t = threadIdx.x; t < IN_X * IN_E; t += 256) sW0[t] = W0[t];
    __syncthreads();
    const int o = blk * 256 + threadIdx.x;
    const int hf = o >> 12;
    const int rem = o & 4095;
    const int j = rem >> 5, i = rem & 31;
    const float* W = hf ? W1r : W1l;
    float u = 0.f;
    #pragma unroll 8
    for (int k = 0; k < IN_E; ++k) u += sW0[i * IN_E + k] * W[k * HID + j];
    (hf ? U2T : U1T)[j * IN_X + i] = __float2half(u);
  } else if (blk == 32) {
    const int j = threadIdx.x;
    if (j < HID) {
      float cv = b1l[j];
      for (int k = 0; k < IN_E; ++k)
        cv += b0[k] * (W1l[k * HID + j] + W1r[k * HID + j]);
      c1[j] = cv;
    }
  } else if (blk < 65) {
    int i = (blk - 33) * 256 + threadIdx.x;   // over HID*OUTF = 8192
    if (i < HID * OUTF) {
      int k = i >> 6, c = i & 63;
      W2lT[c * HID + k] = __float2half(W2l[i]);
      W2rT[c * HID + k] = __float2half(W2r[i]);
    }
  } else {
    int i = ((blk - 65) * 256 + threadIdx.x) * 8;
    if (i < xtotal) {
      float4 a = *(const float4*)(x + i);
      float4 b = *(const float4*)(x + i + 4);
      __half2 h0 = __floats2half2_rn(a.x, a.y);
      __half2 h1 = __floats2half2_rn(a.z, a.w);
      __half2 h2 = __floats2half2_rn(b.x, b.y);
      __half2 h3 = __floats2half2_rn(b.z, b.w);
      uint4 o = { *(uint*)&h0, *(uint*)&h1, *(uint*)&h2, *(uint*)&h3 };
      *(uint4*)(xh + i) = o;
    }
  }
}

// ---------- fused bucket build: hist -> global reserve -> scatter ----------
__global__ __launch_bounds__(512) void k_scatfuse(const int* __restrict__ src,
    const int* __restrict__ dst, int* __restrict__ gcursor,
    uint* __restrict__ bucketData, int E) {
  __shared__ int hist[NBP];
  const int cblk = blockIdx.x;
  for (int i = threadIdx.x; i < NBP; i += 512) hist[i] = 0;
  __syncthreads();
  const int base = cblk * CHUNK;
  int d[CHUNK / 512], s[CHUNK / 512];
  #pragma unroll
  for (int k = 0; k < CHUNK / 512; ++k) {
    int e = base + k * 512 + threadIdx.x;
    d[k] = (e < E) ? dst[e] : -1;
    s[k] = (e < E) ? src[e] : 0;
  }
  #pragma unroll
  for (int k = 0; k < CHUNK / 512; ++k)
    if (d[k] >= 0) atomicAdd(&hist[d[k] >> BSHIFT], 1);
  __syncthreads();
  for (int i = threadIdx.x; i < NBP; i += 512) {
    int h = hist[i];
    hist[i] = (h > 0) ? atomicAdd(&gcursor[i], h) : 0;
  }
  __syncthreads();
  #pragma unroll
  for (int k = 0; k < CHUNK / 512; ++k) {
    if (d[k] >= 0) {
      int bkt = d[k] >> BSHIFT;
      int pos = atomicAdd(&hist[bkt], 1);
      if (pos < CAP)
        bucketData[(size_t)bkt * CAP + pos] =
            ((uint)s[k] << BSHIFT) | (uint)(d[k] & (BSZ - 1));
    }
  }
}

// ---------- conv1 aggregation + gapped-CSR export ----------
// Counting sort per bucket, gather-sum xh (64B row = 8 lanes x uint2,
// packed-fp16 accumulate), export gorder + gns/gne.
__global__ __launch_bounds__(512) void k_baggr32s(const __half* __restrict__ feat,
    const uint* __restrict__ bucketData, const int* __restrict__ gcnt,
    __half* __restrict__ aggr, uint* __restrict__ gorder,
    int* __restrict__ gns, int* __restrict__ gne, int N) {
  constexpr int FW = IN_X;     // 32 halves per row
  constexpr int LPR = FW / 4;  // 8 lanes per row (uint2 each)
  constexpr int RPW = 64 / LPR;
  __shared__ int nodeStart[BSZ + 1];
  __shared__ int cursor[BSZ];
  __shared__ int order[CAP];
  const int b = blockIdx.x;
  const int tid = threadIdx.x;
  const int lane = tid & 63, wid = tid >> 6;
  const int e0 = b * CAP;
  const int cnt = min(gcnt[b], CAP);

  if (tid < BSZ) cursor[tid] = 0;
  __syncthreads();
  for (int i = tid; i < cnt; i += 512)
    atomicAdd(&cursor[bucketData[e0 + i] & (BSZ - 1)], 1);
  __syncthreads();

  if (wid == 0) {
    int v0 = cursor[lane], v1 = cursor[64 + lane];
    int x0 = v0, x1 = v1;
    #pragma unroll
    for (int s = 1; s < 64; s <<= 1) {
      int y0 = __shfl_up(x0, s, 64);
      int y1 = __shfl_up(x1, s, 64);
      if (lane >= s) { x0 += y0; x1 += y1; }
    }
    int tot0 = __shfl(x0, 63, 64);
    nodeStart[lane] = x0 - v0;
    nodeStart[64 + lane] = tot0 + x1 - v1;
    if (lane == 63) nodeStart[BSZ] = tot0 + x1;
  }
  __syncthreads();
  if (tid < BSZ) cursor[tid] = nodeStart[tid];
  __syncthreads();

  for (int i = tid; i < cnt; i += 512) {
    uint p = bucketData[e0 + i];
    int pos = atomicAdd(&cursor[p & (BSZ - 1)], 1);
    order[pos] = (int)(p >> BSHIFT);
  }
  __syncthreads();

  // export gapped CSR
  for (int i = tid; i < cnt; i += 512) gorder[e0 + i] = (uint)order[i];
  if (tid < BSZ) {
    const int n = b * BSZ + tid;
    if (n < N) { gns[n] = e0 + nodeStart[tid]; gne[n] = e0 + nodeStart[tid + 1]; }
  }

  // gather-sum xh (packed fp16 accumulate)
  const int nodes = min(BSZ, N - b * BSZ);
  const int g = lane / LPR, e = lane % LPR;
  for (int n = wid; n < nodes; n += 8) {
    const int s = nodeStart[n], t = nodeStart[n + 1];
    __half2 ax = __floats2half2_rn(0.f, 0.f), ay = ax;
    int j = s;
    for (; j + 2 * RPW <= t; j += 2 * RPW) {
      int r0 = order[j + g], r1 = order[j + RPW + g];
      uint2 v0 = ((const uint2*)(feat + (size_t)r0 * FW))[e];
      uint2 v1 = ((const uint2*)(feat + (size_t)r1 * FW))[e];
      ax = __hadd2(ax, __hadd2(u2h(v0.x), u2h(v1.x)));
      ay = __hadd2(ay, __hadd2(u2h(v0.y), u2h(v1.y)));
    }
    for (; j < t; j += RPW) {
      if (j + g < t) {
        int r = order[j + g];
        uint2 v = ((const uint2*)(feat + (size_t)r * FW))[e];
        ax = __hadd2(ax, u2h(v.x));
        ay = __hadd2(ay, u2h(v.y));
      }
    }
    float2 fx = __half22float2(ax), fy = __half22float2(ay);
    float4 acc = {fx.x, fx.y, fy.x, fy.y};
    #pragma unroll
    for (int m = LPR; m < 64; m <<= 1) {
      acc.x += __shfl_xor(acc.x, m, 64);
      acc.y += __shfl_xor(acc.y, m, 64);
      acc.z += __shfl_xor(acc.z, m, 64);
      acc.w += __shfl_xor(acc.w, m, 64);
    }
    if (g == 0) {
      float inv = 1.f / fmaxf((float)(t - s), 1.f);
      __half2 o0 = __floats2half2_rn(acc.x * inv, acc.y * inv);
      __half2 o1 = __floats2half2_rn(acc.z * inv, acc.w * inv);
      uint2 o = { *(uint*)&o0, *(uint*)&o1 };
      ((uint2*)(aggr + ((size_t)(b * BSZ + n)) * FW))[e] = o;
    }
  }
}

// ---------- fused conv1 lin + p2/q2 ----------
__global__ __launch_bounds__(256) void k_conv1fused(
    const __half* __restrict__ axm, const __half* __restrict__ xh,
    const __half* __restrict__ U1T, const __half* __restrict__ U2T,
    const float* __restrict__ c1,
    const __half* __restrict__ W2lT, const __half* __restrict__ W2rT,
    __half* __restrict__ p2, __half* __restrict__ q2, int N) {
  __shared__ _Float16 tile[4][16 * HID];
  const int lane = threadIdx.x & 63;
  const int wid = threadIdx.x >> 6;
  const int row0 = blockIdx.x * 64 + wid * 16;
  const int lr = lane & 15;
  const int lk = (lane >> 4) * 8;

  {
    f16x8 b1[8], b2[8];
    #pragma unroll
    for (int ct = 0; ct < 8; ++ct) {
      const int c = ct * 16 + lr;
      b1[ct] = *(const f16x8*)((const _Float16*)U1T + (size_t)c * IN_X + lk);
      b2[ct] = *(const f16x8*)((const _Float16*)U2T + (size_t)c * IN_X + lk);
    }
    f32x4 acc[8];
    #pragma unroll
    for (int ct = 0; ct < 8; ++ct) {
      float bv = c1[ct * 16 + lr];
      acc[ct] = (f32x4){bv, bv, bv, bv};
    }
    const int rA = min(row0 + lr, N - 1);
    f16x8 a1 = *(const f16x8*)((const _Float16*)axm + (size_t)rA * IN_X + lk);
    f16x8 a2 = *(const f16x8*)((const _Float16*)xh + (size_t)rA * IN_X + lk);
    #pragma unroll
    for (int ct = 0; ct < 8; ++ct)
      acc[ct] = __builtin_amdgcn_mfma_f32_16x16x32_f16(a1, b1[ct], acc[ct], 0, 0, 0);
    #pragma unroll
    for (int ct = 0; ct < 8; ++ct)
      acc[ct] = __builtin_amdgcn_mfma_f32_16x16x32_f16(a2, b2[ct], acc[ct], 0, 0, 0);
    #pragma unroll
    for (int ct = 0; ct < 8; ++ct) {
      #pragma unroll
      for (int r = 0; r < 4; ++r) {
        const int row = (lane >> 4) * 4 + r;
        const int col = ct * 16 + lr;
        int idx = (row * HID + col) ^ ((row & 7) << 3);
        tile[wid][idx] = (_Float16)fmaxf(acc[ct][r], 0.f);
      }
    }
  }
  __syncthreads();

  f16x8 a[4];
  #pragma unroll
  for (int t = 0; t < 4; ++t) {
    int idx = (lr * HID + t * 32 + lk) ^ ((lr & 7) << 3);
    a[t] = *(const f16x8*)&tile[wid][idx];
  }
  f16x8 wl[4][4], wr[4][4];
  #pragma unroll
  for (int t = 0; t < 4; ++t)
    #pragma unroll
    for (int ct = 0; ct < 4; ++ct) {
      const int c = ct * 16 + lr;
      wl[t][ct] = *(const f16x8*)((const _Float16*)W2lT + (size_t)c * HID + t * 32 + lk);
      wr[t][ct] = *(const f16x8*)((const _Float16*)W2rT + (size_t)c * HID + t * 32 + lk);
    }
  f32x4 accp[4] = {}, accq[4] = {};
  #pragma unroll
  for (int t = 0; t < 4; ++t) {
    #pragma unroll
    for (int ct = 0; ct < 4; ++ct)
      accp[ct] = __builtin_amdgcn_mfma_f32_16x16x32_f16(a[t], wl[t][ct], accp[ct], 0, 0, 0);
    #pragma unroll
    for (int ct = 0; ct < 4; ++ct)
      accq[ct] = __builtin_amdgcn_mfma_f32_16x16x32_f16(a[t], wr[t][ct], accq[ct], 0, 0, 0);
  }
  #pragma unroll
  for (int ct = 0; ct < 4; ++ct) {
    const int c = ct * 16 + lr;
    #pragma unroll
    for (int r = 0; r < 4; ++r) {
      const int row = row0 + (lane >> 4) * 4 + r;
      if (row < N) {
        p2[(size_t)row * OUTF + c] = __float2half(accp[ct][r]);
        q2[(size_t)row * OUTF + c] = __float2half(accq[ct][r]);
      }
    }
  }
}

// ---------- conv2 gather + fused lin2/head ----------
// One wave per node. Row = 128B = 16 lanes x uint2; 4 loads/iter = 16 rows
// in flight; packed-fp16 accumulate. h2 in registers; gs/gd out.
__global__ __launch_bounds__(512) void k_gaggr64(const __half* __restrict__ p2,
    const int* __restrict__ gns, const int* __restrict__ gne,
    const uint* __restrict__ gorder,
    const __half* __restrict__ q2, const float* __restrict__ b2l,
    const float* __restrict__ Wp, float* __restrict__ gs, float* __restrict__ gd,
    int N) {
  const int lane = threadIdx.x & 63;
  const int gwave = (blockIdx.x * 512 + threadIdx.x) >> 6;
  const int nwaves = (gridDim.x * 512) >> 6;
  const int g = lane >> 4, e = lane & 15;   // 16 lanes x uint2 = 128B row
  const float4 bl  = ((const float4*)b2l)[e];
  const float4 ws4 = ((const float4*)Wp)[e];
  const float4 wd4 = ((const float4*)(Wp + OUTF))[e];
  for (int n = gwave; n < N; n += nwaves) {
    const int s = gns[n], t = gne[n];
    __half2 ax = __floats2half2_rn(0.f, 0.f), ay = ax;
    int j = s;
    for (; j + 16 <= t; j += 16) {
      int r0 = (int)gorder[j + g],      r1 = (int)gorder[j + 4 + g];
      int r2 = (int)gorder[j + 8 + g],  r3 = (int)gorder[j + 12 + g];
      uint2 v0 = ((const uint2*)(p2 + (size_t)r0 * OUTF))[e];
      uint2 v1 = ((const uint2*)(p2 + (size_t)r1 * OUTF))[e];
      uint2 v2 = ((const uint2*)(p2 + (size_t)r2 * OUTF))[e];
      uint2 v3 = ((const uint2*)(p2 + (size_t)r3 * OUTF))[e];
      __half2 x01 = __hadd2(u2h(v0.x), u2h(v1.x));
      __half2 x23 = __hadd2(u2h(v2.x), u2h(v3.x));
      __half2 y01 = __hadd2(u2h(v0.y), u2h(v1.y));
      __half2 y23 = __hadd2(u2h(v2.y), u2h(v3.y));
      ax = __hadd2(ax, __hadd2(x01, x23));
      ay = __hadd2(ay, __hadd2(y01, y23));
    }
    for (; j < t; j += 4) {
      if (j + g < t) {
        int r = (int)gorder[j + g];
        uint2 v = ((const uint2*)(p2 + (size_t)r * OUTF))[e];
        ax = __hadd2(ax, u2h(v.x));
        ay = __hadd2(ay, u2h(v.y));
      }
    }
    float2 fx = __half22float2(ax), fy = __half22float2(ay);
    float4 acc = {fx.x, fx.y, fy.x, fy.y};
    acc.x += __shfl_xor(acc.x, 16, 64); acc.y += __shfl_xor(acc.y, 16, 64);
    acc.z += __shfl_xor(acc.z, 16, 64); acc.w += __shfl_xor(acc.w, 16, 64);
    acc.x += __shfl_xor(acc.x, 32, 64); acc.y += __shfl_xor(acc.y, 32, 64);
    acc.z += __shfl_xor(acc.z, 32, 64); acc.w += __shfl_xor(acc.w, 32, 64);
    const float inv = 1.f / fmaxf((float)(t - s), 1.f);
    uint2 qv = ((const uint2*)(q2 + (size_t)n * OUTF))[e];
    float2 qa = h2f2(qv.x), qb = h2f2(qv.y);
    float h0v = qa.x + acc.x * inv + bl.x;
    float h1v = qa.y + acc.y * inv + bl.y;
    float h2v = qb.x + acc.z * inv + bl.z;
    float h3v = qb.y + acc.w * inv + bl.w;
    float sp = h0v * ws4.x + h1v * ws4.y + h2v * ws4.z + h3v * ws4.w;
    float dp = h0v * wd4.x + h1v * wd4.y + h2v * wd4.z + h3v * wd4.w;
    #pragma unroll
    for (int m = 1; m < 16; m <<= 1) {
      sp += __shfl_xor(sp, m, 64);
      dp += __shfl_xor(dp, m, 64);
    }
    if (lane == 0) { gs[n] = sp; gd[n] = dp; }
  }
}

// ---------- per-edge: raw = gs[src] + gd[dst] + bp; sigmoid ----------
__global__ __launch_bounds__(256) void k_edge(const float* __restrict__ gs,
    const float* __restrict__ gd, const int* __restrict__ srcI,
    const int* __restrict__ dstI, const float* __restrict__ bp,
    float* __restrict__ out, int E) {
  int e = blockIdx.x * 256 + threadIdx.x;
  if (e >= E) return;
  float raw = gs[srcI[e]] + gd[dstI[e]] + bp[0];
  out[e] = raw;
  out[(size_t)E + e] = 1.f / (1.f + expf(-raw));
}

extern "C" void kernel_launch(void* const* d_in, const int* in_sizes, int n_in,
                              void* d_out, int out_size, void* d_ws, size_t ws_size,
                              hipStream_t stream) {
  const float* x   = (const float*)d_in[0];
  const int*   ei  = (const int*)d_in[1];
  const float* W0  = (const float*)d_in[2];
  const float* b0  = (const float*)d_in[3];
  const float* W1l = (const float*)d_in[4];
  const float* b1l = (const float*)d_in[5];
  const float* W1r = (const float*)d_in[6];
  const float* W2l = (const float*)d_in[7];
  const float* b2l = (const float*)d_in[8];
  const float* W2r = (const float*)d_in[9];
  const float* Wp  = (const float*)d_in[10];
  const float* bp  = (const float*)d_in[11];

  const int N = in_sizes[0] / IN_X;
  const int E = in_sizes[1] / 2;
  const int* srcI = ei;
  const int* dstI = ei + E;
  float* out = (float*)d_out;

  const int NB = (N + BSZ - 1) >> BSHIFT;
  const int nchunk = (E + CHUNK - 1) / CHUNK;

  // workspace layout
  __half* xh  = (__half*)d_ws;                   // [N][32]
  __half* axm = xh + (size_t)N * IN_X;           // [N][32]
  __half* p2  = axm + (size_t)N * IN_X;          // [N][64]
  __half* q2  = p2 + (size_t)N * OUTF;           // [N][64]
  float* gs   = (float*)(q2 + (size_t)N * OUTF);
  float* gd   = gs + N;
  uintptr_t wp = ((uintptr_t)(gd + N) + 15) & ~(uintptr_t)15;
  __half* U1T  = (__half*)wp;                    // [128][32]
  __half* U2T  = U1T + HID * IN_X;
  __half* W2lT = U2T + HID * IN_X;               // [64][128]
  __half* W2rT = W2lT + OUTF * HID;
  float* c1    = (float*)(W2rT + OUTF * HID);    // [128]
  int* gcursor = (int*)(c1 + HID);               // [NBP]
  int* gns     = gcursor + NBP;                  // [N+1]
  int* gne     = gns + N + 1;                    // [N]
  uint* bucketData = (uint*)(gne + N);           // [NBP*CAP]
  uint* gorder     = bucketData + (size_t)NBP * CAP;  // [NBP*CAP]

  hipMemsetAsync(gcursor, 0, sizeof(int) * NBP, stream);

  const int xblocks = (N * IN_X / 8 + 255) / 256;
  k_prep<<<65 + xblocks, 256, 0, stream>>>(W0, b0, W1l, b1l, W1r, W2l, W2r,
                                           U1T, U2T, c1, W2lT, W2rT,
                                           x, xh, N * IN_X);
  // fused bucket build
  k_scatfuse<<<nchunk, 512, 0, stream>>>(srcI, dstI, gcursor, bucketData, E);
  // conv1: axm = mean(xh_j), counting sort + gapped CSR export
  k_baggr32s<<<NB, 512, 0, stream>>>(xh, bucketData, gcursor, axm, gorder, gns, gne, N);
  // fused conv1 lin + p2/q2
  k_conv1fused<<<(N + 63) / 64, 256, 0, stream>>>(axm, xh, U1T, U2T, c1,
                                                  W2lT, W2rT, p2, q2, N);
  // conv2 gather + fused lin2/head
  k_gaggr64<<<1024, 512, 0, stream>>>(p2, gns, gne, gorder, q2, b2l, Wp, gs, gd, N);
  // edge head
  k_edge<<<(E + 255) / 256, 256, 0, stream>>>(gs, gd, srcI, dstI, bp, out, E);
}

// Round 12
// 129.586 us; speedup vs baseline: 1.7178x; 1.3591x over previous
//
#include <hip/hip_runtime.h>
#include <hip/hip_bf16.h>
#include <hip/hip_fp16.h>

// GraphSAGE fwd, round 12.
// lin0 folded into conv1 (U1=W0@W1l, U2=W0@W1r, c1=b0@(W1l+W1r)+b1l).
// CONV2 COLLAPSED TO SCALARS: gs[n] = mean_j(h1_j·vs) + h1[n]·us + bs with
// vs=W2l@wps, us=W2r@wps (same for d) — the conv2 vector gather (128B rows,
// 12.8MB table, 48µs) becomes an 8B scalar gather from an 800KB L2-resident
// table. h2/p2/q2 never materialized.
// Bucket build: ONE fused kernel (hist -> global range-reserve -> scatter).
// Counting sort ONCE (gapped CSR gns/gne/gorder) in baggr32s.
// conv1fused: MFMA h1 tile in LDS + 4 dot-product epilogue -> tsd/ssd.

#define IN_X 32
#define IN_E 64
#define HID 128
#define OUTF 64

#define BSHIFT 7
#define BSZ 128          // nodes per bucket
#define NBP 1024         // padded bucket count
#define CHUNK 4096       // edges per scatter block
#define CAP 4096         // slots per bucket (mean 2560, +30 sigma)

typedef _Float16 f16x8 __attribute__((ext_vector_type(8)));
typedef float f32x4 __attribute__((ext_vector_type(4)));

__device__ __forceinline__ float2 h2f2(uint v) {
  __half2 h = *reinterpret_cast<__half2*>(&v);
  return __half22float2(h);
}
__device__ __forceinline__ __half2 u2h(uint v) {
  return *reinterpret_cast<__half2*>(&v);
}

// ---------- prep: U1T/U2T, c1, head consts, svecs (vs|vd|us|ud), xh ----------
__global__ __launch_bounds__(256) void k_prep(
    const float* __restrict__ W0, const float* __restrict__ b0,
    const float* __restrict__ W1l, const float* __restrict__ b1l,
    const float* __restrict__ W1r,
    const float* __restrict__ W2l, const float* __restrict__ W2r,
    const float* __restrict__ b2l, const float* __restrict__ Wp,
    __half* __restrict__ U1T, __half* __restrict__ U2T, float* __restrict__ c1,
    float* __restrict__ svecs, float* __restrict__ hb,
    const float* __restrict__ x, __half* __restrict__ xh, int xtotal) {
  const int blk = blockIdx.x;
  if (blk < 32) {
    __shared__ float sW0[IN_X * IN_E];
    for (int t = threadIdx.x; t < IN_X * IN_E; t += 256) sW0[t] = W0[t];
    __syncthreads();
    const int o = blk * 256 + threadIdx.x;
    const int hf = o >> 12;
    const int rem = o & 4095;
    const int j = rem >> 5, i = rem & 31;
    const float* W = hf ? W1r : W1l;
    float u = 0.f;
    #pragma unroll 8
    for (int k = 0; k < IN_E; ++k) u += sW0[i * IN_E + k] * W[k * HID + j];
    (hf ? U2T : U1T)[j * IN_X + i] = __float2half(u);
  } else if (blk == 32) {
    const int j = threadIdx.x;
    if (j < HID) {
      float cv = b1l[j];
      for (int k = 0; k < IN_E; ++k)
        cv += b0[k] * (W1l[k * HID + j] + W1r[k * HID + j]);
      c1[j] = cv;
    } else if (j == HID || j == HID + 1) {
      // hb[0] = b2l . wps ; hb[1] = b2l . wpd
      const float* w = Wp + (j - HID) * OUTF;
      float s = 0.f;
      for (int k = 0; k < OUTF; ++k) s += b2l[k] * w[k];
      hb[j - HID] = s;
    }
  } else if (blk == 33 || blk == 34) {
    // GEMVs: blk33 -> vs,vd from W2l ; blk34 -> us,ud from W2r
    __shared__ float sW[HID * OUTF];   // 32 KB
    const float* W = (blk == 33) ? W2l : W2r;
    for (int t = threadIdx.x; t < HID * OUTF; t += 256) sW[t] = W[t];
    __syncthreads();
    const int vec = threadIdx.x >> 7;         // 0 -> wps, 1 -> wpd
    const int j = threadIdx.x & 127;          // output row
    const float* w = Wp + vec * OUTF;
    float s = 0.f;
    #pragma unroll 8
    for (int k = 0; k < OUTF; ++k) s += sW[j * OUTF + k] * w[k];
    svecs[(blk - 33) * 256 + vec * 128 + j] = s;
  } else {
    int i = ((blk - 35) * 256 + threadIdx.x) * 8;
    if (i < xtotal) {
      float4 a = *(const float4*)(x + i);
      float4 b = *(const float4*)(x + i + 4);
      __half2 h0 = __floats2half2_rn(a.x, a.y);
      __half2 h1 = __floats2half2_rn(a.z, a.w);
      __half2 h2 = __floats2half2_rn(b.x, b.y);
      __half2 h3 = __floats2half2_rn(b.z, b.w);
      uint4 o = { *(uint*)&h0, *(uint*)&h1, *(uint*)&h2, *(uint*)&h3 };
      *(uint4*)(xh + i) = o;
    }
  }
}

// ---------- fused bucket build: hist -> global reserve -> scatter ----------
__global__ __launch_bounds__(512) void k_scatfuse(const int* __restrict__ src,
    const int* __restrict__ dst, int* __restrict__ gcursor,
    uint* __restrict__ bucketData, int E) {
  __shared__ int hist[NBP];
  const int cblk = blockIdx.x;
  for (int i = threadIdx.x; i < NBP; i += 512) hist[i] = 0;
  __syncthreads();
  const int base = cblk * CHUNK;
  int d[CHUNK / 512], s[CHUNK / 512];
  #pragma unroll
  for (int k = 0; k < CHUNK / 512; ++k) {
    int e = base + k * 512 + threadIdx.x;
    d[k] = (e < E) ? dst[e] : -1;
    s[k] = (e < E) ? src[e] : 0;
  }
  #pragma unroll
  for (int k = 0; k < CHUNK / 512; ++k)
    if (d[k] >= 0) atomicAdd(&hist[d[k] >> BSHIFT], 1);
  __syncthreads();
  for (int i = threadIdx.x; i < NBP; i += 512) {
    int h = hist[i];
    hist[i] = (h > 0) ? atomicAdd(&gcursor[i], h) : 0;
  }
  __syncthreads();
  #pragma unroll
  for (int k = 0; k < CHUNK / 512; ++k) {
    if (d[k] >= 0) {
      int bkt = d[k] >> BSHIFT;
      int pos = atomicAdd(&hist[bkt], 1);
      if (pos < CAP)
        bucketData[(size_t)bkt * CAP + pos] =
            ((uint)s[k] << BSHIFT) | (uint)(d[k] & (BSZ - 1));
    }
  }
}

// ---------- conv1 aggregation + gapped-CSR export ----------
__global__ __launch_bounds__(512) void k_baggr32s(const __half* __restrict__ feat,
    const uint* __restrict__ bucketData, const int* __restrict__ gcnt,
    __half* __restrict__ aggr, uint* __restrict__ gorder,
    int* __restrict__ gns, int* __restrict__ gne, int N) {
  constexpr int FW = IN_X;     // 32 halves per row
  constexpr int LPR = FW / 4;  // 8 lanes per row (uint2 each)
  constexpr int RPW = 64 / LPR;
  __shared__ int nodeStart[BSZ + 1];
  __shared__ int cursor[BSZ];
  __shared__ int order[CAP];
  const int b = blockIdx.x;
  const int tid = threadIdx.x;
  const int lane = tid & 63, wid = tid >> 6;
  const int e0 = b * CAP;
  const int cnt = min(gcnt[b], CAP);

  if (tid < BSZ) cursor[tid] = 0;
  __syncthreads();
  for (int i = tid; i < cnt; i += 512)
    atomicAdd(&cursor[bucketData[e0 + i] & (BSZ - 1)], 1);
  __syncthreads();

  if (wid == 0) {
    int v0 = cursor[lane], v1 = cursor[64 + lane];
    int x0 = v0, x1 = v1;
    #pragma unroll
    for (int s = 1; s < 64; s <<= 1) {
      int y0 = __shfl_up(x0, s, 64);
      int y1 = __shfl_up(x1, s, 64);
      if (lane >= s) { x0 += y0; x1 += y1; }
    }
    int tot0 = __shfl(x0, 63, 64);
    nodeStart[lane] = x0 - v0;
    nodeStart[64 + lane] = tot0 + x1 - v1;
    if (lane == 63) nodeStart[BSZ] = tot0 + x1;
  }
  __syncthreads();
  if (tid < BSZ) cursor[tid] = nodeStart[tid];
  __syncthreads();

  for (int i = tid; i < cnt; i += 512) {
    uint p = bucketData[e0 + i];
    int pos = atomicAdd(&cursor[p & (BSZ - 1)], 1);
    order[pos] = (int)(p >> BSHIFT);
  }
  __syncthreads();

  // export gapped CSR
  for (int i = tid; i < cnt; i += 512) gorder[e0 + i] = (uint)order[i];
  if (tid < BSZ) {
    const int n = b * BSZ + tid;
    if (n < N) { gns[n] = e0 + nodeStart[tid]; gne[n] = e0 + nodeStart[tid + 1]; }
  }

  // gather-sum xh (packed fp16 accumulate)
  const int nodes = min(BSZ, N - b * BSZ);
  const int g = lane / LPR, e = lane % LPR;
  for (int n = wid; n < nodes; n += 8) {
    const int s = nodeStart[n], t = nodeStart[n + 1];
    __half2 ax = __floats2half2_rn(0.f, 0.f), ay = ax;
    int j = s;
    for (; j + 2 * RPW <= t; j += 2 * RPW) {
      int r0 = order[j + g], r1 = order[j + RPW + g];
      uint2 v0 = ((const uint2*)(feat + (size_t)r0 * FW))[e];
      uint2 v1 = ((const uint2*)(feat + (size_t)r1 * FW))[e];
      ax = __hadd2(ax, __hadd2(u2h(v0.x), u2h(v1.x)));
      ay = __hadd2(ay, __hadd2(u2h(v0.y), u2h(v1.y)));
    }
    for (; j < t; j += RPW) {
      if (j + g < t) {
        int r = order[j + g];
        uint2 v = ((const uint2*)(feat + (size_t)r * FW))[e];
        ax = __hadd2(ax, u2h(v.x));
        ay = __hadd2(ay, u2h(v.y));
      }
    }
    float2 fx = __half22float2(ax), fy = __half22float2(ay);
    float4 acc = {fx.x, fx.y, fy.x, fy.y};
    #pragma unroll
    for (int m = LPR; m < 64; m <<= 1) {
      acc.x += __shfl_xor(acc.x, m, 64);
      acc.y += __shfl_xor(acc.y, m, 64);
      acc.z += __shfl_xor(acc.z, m, 64);
      acc.w += __shfl_xor(acc.w, m, 64);
    }
    if (g == 0) {
      float inv = 1.f / fmaxf((float)(t - s), 1.f);
      __half2 o0 = __floats2half2_rn(acc.x * inv, acc.y * inv);
      __half2 o1 = __floats2half2_rn(acc.z * inv, acc.w * inv);
      uint2 o = { *(uint*)&o0, *(uint*)&o1 };
      ((uint2*)(aggr + ((size_t)(b * BSZ + n)) * FW))[e] = o;
    }
  }
}

// ---------- fused conv1 lin + scalar head projections ----------
// h1 = relu(axm@U1 + xh@U2 + c1) per 16-row wave tile (swizzled LDS), then
// per node 4 dots: ts=h1.vs, td=h1.vd, ss=h1.us, sd=h1.ud -> tsd/ssd.
__global__ __launch_bounds__(256) void k_conv1fused(
    const __half* __restrict__ axm, const __half* __restrict__ xh,
    const __half* __restrict__ U1T, const __half* __restrict__ U2T,
    const float* __restrict__ c1, const float* __restrict__ svecs,
    float2* __restrict__ tsd, float2* __restrict__ ssd, int N) {
  __shared__ _Float16 tile[4][16 * HID];
  __shared__ float svec[512];    // [vs|vd|us|ud]
  const int lane = threadIdx.x & 63;
  const int wid = threadIdx.x >> 6;
  const int row0 = blockIdx.x * 64 + wid * 16;
  const int lr = lane & 15;
  const int lk = (lane >> 4) * 8;

  for (int i = threadIdx.x; i < 512; i += 256) svec[i] = svecs[i];

  {
    f16x8 b1[8], b2[8];
    #pragma unroll
    for (int ct = 0; ct < 8; ++ct) {
      const int c = ct * 16 + lr;
      b1[ct] = *(const f16x8*)((const _Float16*)U1T + (size_t)c * IN_X + lk);
      b2[ct] = *(const f16x8*)((const _Float16*)U2T + (size_t)c * IN_X + lk);
    }
    f32x4 acc[8];
    #pragma unroll
    for (int ct = 0; ct < 8; ++ct) {
      float bv = c1[ct * 16 + lr];
      acc[ct] = (f32x4){bv, bv, bv, bv};
    }
    const int rA = min(row0 + lr, N - 1);
    f16x8 a1 = *(const f16x8*)((const _Float16*)axm + (size_t)rA * IN_X + lk);
    f16x8 a2 = *(const f16x8*)((const _Float16*)xh + (size_t)rA * IN_X + lk);
    #pragma unroll
    for (int ct = 0; ct < 8; ++ct)
      acc[ct] = __builtin_amdgcn_mfma_f32_16x16x32_f16(a1, b1[ct], acc[ct], 0, 0, 0);
    #pragma unroll
    for (int ct = 0; ct < 8; ++ct)
      acc[ct] = __builtin_amdgcn_mfma_f32_16x16x32_f16(a2, b2[ct], acc[ct], 0, 0, 0);
    // relu -> swizzled LDS
    #pragma unroll
    for (int ct = 0; ct < 8; ++ct) {
      #pragma unroll
      for (int r = 0; r < 4; ++r) {
        const int row = (lane >> 4) * 4 + r;
        const int col = ct * 16 + lr;
        int idx = (row * HID + col) ^ ((row & 7) << 3);
        tile[wid][idx] = (_Float16)fmaxf(acc[ct][r], 0.f);
      }
    }
  }
  __syncthreads();

  // dots: lane = row (0..15) x quarter (0..3); each lane covers 32 cols
  const int row = lane & 15, q = lane >> 4;
  float ts = 0.f, td = 0.f, ss = 0.f, sd = 0.f;
  #pragma unroll
  for (int t = 0; t < 4; ++t) {
    const int col = q * 32 + t * 8;
    int idx = (row * HID + col) ^ ((row & 7) << 3);
    f16x8 h = *(const f16x8*)&tile[wid][idx];
    #pragma unroll
    for (int i = 0; i < 8; ++i) {
      float hv = (float)h[i];
      ts += hv * svec[col + i];
      td += hv * svec[128 + col + i];
      ss += hv * svec[256 + col + i];
      sd += hv * svec[384 + col + i];
    }
  }
  ts += __shfl_xor(ts, 16, 64); ts += __shfl_xor(ts, 32, 64);
  td += __shfl_xor(td, 16, 64); td += __shfl_xor(td, 32, 64);
  ss += __shfl_xor(ss, 16, 64); ss += __shfl_xor(ss, 32, 64);
  sd += __shfl_xor(sd, 16, 64); sd += __shfl_xor(sd, 32, 64);
  if (q == 0) {
    const int grow = row0 + row;
    if (grow < N) {
      tsd[grow] = make_float2(ts, td);
      ssd[grow] = make_float2(ss, sd);
    }
  }
}

// ---------- conv2 scalar aggregation: gs/gd from L2-resident 8B gathers ----
__global__ __launch_bounds__(256) void k_scalagg(const float2* __restrict__ tsd,
    const float2* __restrict__ ssd, const int* __restrict__ gns,
    const int* __restrict__ gne, const uint* __restrict__ gorder,
    const float* __restrict__ hb,
    float* __restrict__ gs, float* __restrict__ gd, int N) {
  const int n = blockIdx.x * 256 + threadIdx.x;
  if (n >= N) return;
  const int s = gns[n], t = gne[n];
  float ax = 0.f, ay = 0.f;
  int j = s;
  for (; j + 4 <= t; j += 4) {
    int r0 = (int)gorder[j],     r1 = (int)gorder[j + 1];
    int r2 = (int)gorder[j + 2], r3 = (int)gorder[j + 3];
    float2 a = tsd[r0], b = tsd[r1], c = tsd[r2], d = tsd[r3];
    ax += (a.x + b.x) + (c.x + d.x);
    ay += (a.y + b.y) + (c.y + d.y);
  }
  for (; j < t; ++j) {
    float2 a = tsd[(int)gorder[j]];
    ax += a.x; ay += a.y;
  }
  const float inv = 1.f / fmaxf((float)(t - s), 1.f);
  const float2 sv = ssd[n];
  gs[n] = sv.x + ax * inv + hb[0];
  gd[n] = sv.y + ay * inv + hb[1];
}

// ---------- per-edge: raw = gs[src] + gd[dst] + bp; sigmoid ----------
__global__ __launch_bounds__(256) void k_edge(const float* __restrict__ gs,
    const float* __restrict__ gd, const int* __restrict__ srcI,
    const int* __restrict__ dstI, const float* __restrict__ bp,
    float* __restrict__ out, int E) {
  int e = blockIdx.x * 256 + threadIdx.x;
  if (e >= E) return;
  float raw = gs[srcI[e]] + gd[dstI[e]] + bp[0];
  out[e] = raw;
  out[(size_t)E + e] = 1.f / (1.f + expf(-raw));
}

extern "C" void kernel_launch(void* const* d_in, const int* in_sizes, int n_in,
                              void* d_out, int out_size, void* d_ws, size_t ws_size,
                              hipStream_t stream) {
  const float* x   = (const float*)d_in[0];
  const int*   ei  = (const int*)d_in[1];
  const float* W0  = (const float*)d_in[2];
  const float* b0  = (const float*)d_in[3];
  const float* W1l = (const float*)d_in[4];
  const float* b1l = (const float*)d_in[5];
  const float* W1r = (const float*)d_in[6];
  const float* W2l = (const float*)d_in[7];
  const float* b2l = (const float*)d_in[8];
  const float* W2r = (const float*)d_in[9];
  const float* Wp  = (const float*)d_in[10];
  const float* bp  = (const float*)d_in[11];

  const int N = in_sizes[0] / IN_X;
  const int E = in_sizes[1] / 2;
  const int* srcI = ei;
  const int* dstI = ei + E;
  float* out = (float*)d_out;

  const int NB = (N + BSZ - 1) >> BSHIFT;
  const int nchunk = (E + CHUNK - 1) / CHUNK;

  // workspace layout
  __half* xh  = (__half*)d_ws;                   // [N][32]
  __half* axm = xh + (size_t)N * IN_X;           // [N][32]
  float2* tsd = (float2*)(axm + (size_t)N * IN_X);  // [N]
  float2* ssd = tsd + N;                         // [N]
  float* gs   = (float*)(ssd + N);               // [N]
  float* gd   = gs + N;                          // [N]
  uintptr_t wp = ((uintptr_t)(gd + N) + 15) & ~(uintptr_t)15;
  __half* U1T  = (__half*)wp;                    // [128][32]
  __half* U2T  = U1T + HID * IN_X;
  float* c1    = (float*)(U2T + HID * IN_X);     // [128]
  float* svecs = c1 + HID;                       // [512] = vs|vd|us|ud
  float* hb    = svecs + 512;                    // [2]
  int* gcursor = (int*)(hb + 2);                 // [NBP]
  int* gns     = gcursor + NBP;                  // [N+1]
  int* gne     = gns + N + 1;                    // [N]
  uint* bucketData = (uint*)(gne + N);           // [NBP*CAP]
  uint* gorder     = bucketData + (size_t)NBP * CAP;  // [NBP*CAP]

  hipMemsetAsync(gcursor, 0, sizeof(int) * NBP, stream);

  const int xblocks = (N * IN_X / 8 + 255) / 256;
  k_prep<<<35 + xblocks, 256, 0, stream>>>(W0, b0, W1l, b1l, W1r, W2l, W2r,
                                           b2l, Wp, U1T, U2T, c1, svecs, hb,
                                           x, xh, N * IN_X);
  // fused bucket build
  k_scatfuse<<<nchunk, 512, 0, stream>>>(srcI, dstI, gcursor, bucketData, E);
  // conv1: axm = mean(xh_j), counting sort + gapped CSR export
  k_baggr32s<<<NB, 512, 0, stream>>>(xh, bucketData, gcursor, axm, gorder, gns, gne, N);
  // fused conv1 lin + scalar head projections
  k_conv1fused<<<(N + 63) / 64, 256, 0, stream>>>(axm, xh, U1T, U2T, c1,
                                                  svecs, tsd, ssd, N);
  // conv2 scalar aggregation
  k_scalagg<<<(N + 255) / 256, 256, 0, stream>>>(tsd, ssd, gns, gne, gorder,
                                                 hb, gs, gd, N);
  // edge head
  k_edge<<<(E + 255) / 256, 256, 0, stream>>>(gs, gd, srcI, dstI, bp, out, E);
}

// Round 13
// 128.886 us; speedup vs baseline: 1.7271x; 1.0054x over previous
//
#include <hip/hip_runtime.h>
#include <hip/hip_bf16.h>
#include <hip/hip_fp16.h>

// GraphSAGE fwd, round 13.
// lin0 folded into conv1 (U1=W0@W1l, U2=W0@W1r, c1=b0@(W1l+W1r)+b1l).
// Conv2 collapsed to scalars (vs=W2l@wps etc) -> 8B gathers from L2-resident
// 800KB table. Bucket build: one fused kernel. NEW: conv1 gather is
// CACHE-PHASED — counting sort key (dstLocal, srcHalf), gather low-half
// sources first (3.2MB working set, fits 4MB/XCD L2), barrier, then high
// half; phase-1 partials stashed packed-fp16 in LDS. gcursor zeroing folded
// into k_prep (one launch fewer).

#define IN_X 32
#define IN_E 64
#define HID 128
#define OUTF 64

#define BSHIFT 7
#define BSZ 128          // nodes per bucket
#define NBP 1024         // padded bucket count
#define CHUNK 4096       // edges per scatter block
#define CAP 4096         // slots per bucket (mean 2560, +30 sigma)

typedef _Float16 f16x8 __attribute__((ext_vector_type(8)));
typedef float f32x4 __attribute__((ext_vector_type(4)));

__device__ __forceinline__ float2 h2f2(uint v) {
  __half2 h = *reinterpret_cast<__half2*>(&v);
  return __half22float2(h);
}
__device__ __forceinline__ __half2 u2h(uint v) {
  return *reinterpret_cast<__half2*>(&v);
}
__device__ __forceinline__ uint h2u(__half2 h) {
  return *reinterpret_cast<uint*>(&h);
}

// ---------- prep: U1T/U2T, c1, head consts, svecs, zero gcursor, xh ----------
__global__ __launch_bounds__(256) void k_prep(
    const float* __restrict__ W0, const float* __restrict__ b0,
    const float* __restrict__ W1l, const float* __restrict__ b1l,
    const float* __restrict__ W1r,
    const float* __restrict__ W2l, const float* __restrict__ W2r,
    const float* __restrict__ b2l, const float* __restrict__ Wp,
    __half* __restrict__ U1T, __half* __restrict__ U2T, float* __restrict__ c1,
    float* __restrict__ svecs, float* __restrict__ hb, int* __restrict__ gcursor,
    const float* __restrict__ x, __half* __restrict__ xh, int xtotal) {
  const int blk = blockIdx.x;
  if (blk < 32) {
    __shared__ float sW0[IN_X * IN_E];
    for (int t = threadIdx.x; t < IN_X * IN_E; t += 256) sW0[t] = W0[t];
    __syncthreads();
    const int o = blk * 256 + threadIdx.x;
    const int hf = o >> 12;
    const int rem = o & 4095;
    const int j = rem >> 5, i = rem & 31;
    const float* W = hf ? W1r : W1l;
    float u = 0.f;
    #pragma unroll 8
    for (int k = 0; k < IN_E; ++k) u += sW0[i * IN_E + k] * W[k * HID + j];
    (hf ? U2T : U1T)[j * IN_X + i] = __float2half(u);
  } else if (blk == 32) {
    const int j = threadIdx.x;
    if (j < HID) {
      float cv = b1l[j];
      for (int k = 0; k < IN_E; ++k)
        cv += b0[k] * (W1l[k * HID + j] + W1r[k * HID + j]);
      c1[j] = cv;
    } else if (j == HID || j == HID + 1) {
      const float* w = Wp + (j - HID) * OUTF;
      float s = 0.f;
      for (int k = 0; k < OUTF; ++k) s += b2l[k] * w[k];
      hb[j - HID] = s;
    }
  } else if (blk == 33 || blk == 34) {
    // GEMVs: blk33 -> vs,vd from W2l ; blk34 -> us,ud from W2r
    __shared__ float sW[HID * OUTF];   // 32 KB
    const float* W = (blk == 33) ? W2l : W2r;
    for (int t = threadIdx.x; t < HID * OUTF; t += 256) sW[t] = W[t];
    __syncthreads();
    const int vec = threadIdx.x >> 7;
    const int j = threadIdx.x & 127;
    const float* w = Wp + vec * OUTF;
    float s = 0.f;
    #pragma unroll 8
    for (int k = 0; k < OUTF; ++k) s += sW[j * OUTF + k] * w[k];
    svecs[(blk - 33) * 256 + vec * 128 + j] = s;
  } else if (blk == 35) {
    #pragma unroll
    for (int k = 0; k < NBP / 256; ++k) gcursor[k * 256 + threadIdx.x] = 0;
  } else {
    int i = ((blk - 36) * 256 + threadIdx.x) * 8;
    if (i < xtotal) {
      float4 a = *(const float4*)(x + i);
      float4 b = *(const float4*)(x + i + 4);
      __half2 h0 = __floats2half2_rn(a.x, a.y);
      __half2 h1 = __floats2half2_rn(a.z, a.w);
      __half2 h2 = __floats2half2_rn(b.x, b.y);
      __half2 h3 = __floats2half2_rn(b.z, b.w);
      uint4 o = { *(uint*)&h0, *(uint*)&h1, *(uint*)&h2, *(uint*)&h3 };
      *(uint4*)(xh + i) = o;
    }
  }
}

// ---------- fused bucket build: hist -> global reserve -> scatter ----------
__global__ __launch_bounds__(512) void k_scatfuse(const int* __restrict__ src,
    const int* __restrict__ dst, int* __restrict__ gcursor,
    uint* __restrict__ bucketData, int E) {
  __shared__ int hist[NBP];
  const int cblk = blockIdx.x;
  for (int i = threadIdx.x; i < NBP; i += 512) hist[i] = 0;
  __syncthreads();
  const int base = cblk * CHUNK;
  int d[CHUNK / 512], s[CHUNK / 512];
  #pragma unroll
  for (int k = 0; k < CHUNK / 512; ++k) {
    int e = base + k * 512 + threadIdx.x;
    d[k] = (e < E) ? dst[e] : -1;
    s[k] = (e < E) ? src[e] : 0;
  }
  #pragma unroll
  for (int k = 0; k < CHUNK / 512; ++k)
    if (d[k] >= 0) atomicAdd(&hist[d[k] >> BSHIFT], 1);
  __syncthreads();
  for (int i = threadIdx.x; i < NBP; i += 512) {
    int h = hist[i];
    hist[i] = (h > 0) ? atomicAdd(&gcursor[i], h) : 0;
  }
  __syncthreads();
  #pragma unroll
  for (int k = 0; k < CHUNK / 512; ++k) {
    if (d[k] >= 0) {
      int bkt = d[k] >> BSHIFT;
      int pos = atomicAdd(&hist[bkt], 1);
      if (pos < CAP)
        bucketData[(size_t)bkt * CAP + pos] =
            ((uint)s[k] << BSHIFT) | (uint)(d[k] & (BSZ - 1));
    }
  }
}

// ---------- conv1 aggregation (cache-phased) + gapped-CSR export ----------
// Counting sort by key=(dstLocal<<1)|srcHalf. Gather low-half sources first
// (block-wide; 3.2MB table slice fits per-XCD L2), stash packed partials in
// LDS, barrier, gather high half. Export gorder + gns/gne (runs contiguous).
__global__ __launch_bounds__(512) void k_baggr32s(const __half* __restrict__ feat,
    const uint* __restrict__ bucketData, const int* __restrict__ gcnt,
    __half* __restrict__ aggr, uint* __restrict__ gorder,
    int* __restrict__ gns, int* __restrict__ gne, int N, int Nhalf) {
  constexpr int FW = IN_X;     // 32 halves per row
  __shared__ int nodeStart[2 * BSZ + 1];
  __shared__ int cursor[2 * BSZ];
  __shared__ int order[CAP];
  __shared__ uint2 stash[BSZ * 8];   // 8 KB packed-fp16 partials
  const int b = blockIdx.x;
  const int tid = threadIdx.x;
  const int lane = tid & 63, wid = tid >> 6;
  const int e0 = b * CAP;
  const int cnt = min(gcnt[b], CAP);

  for (int i = tid; i < 2 * BSZ; i += 512) cursor[i] = 0;
  __syncthreads();
  for (int i = tid; i < cnt; i += 512) {
    uint p = bucketData[e0 + i];
    int key = ((p & (BSZ - 1)) << 1) | ((int)(p >> BSHIFT) >= Nhalf ? 1 : 0);
    atomicAdd(&cursor[key], 1);
  }
  __syncthreads();

  // exclusive scan over 256 counters (wave 0, 4 segments of 64 with carry)
  if (wid == 0) {
    int carry = 0;
    #pragma unroll
    for (int seg = 0; seg < 4; ++seg) {
      int v = cursor[seg * 64 + lane];
      int x = v;
      #pragma unroll
      for (int s = 1; s < 64; s <<= 1) {
        int y = __shfl_up(x, s, 64);
        if (lane >= s) x += y;
      }
      nodeStart[seg * 64 + lane] = carry + x - v;
      carry += __shfl(x, 63, 64);
    }
    if (lane == 0) nodeStart[2 * BSZ] = carry;
  }
  __syncthreads();
  for (int i = tid; i < 2 * BSZ; i += 512) cursor[i] = nodeStart[i];
  __syncthreads();

  for (int i = tid; i < cnt; i += 512) {
    uint p = bucketData[e0 + i];
    int key = ((p & (BSZ - 1)) << 1) | ((int)(p >> BSHIFT) >= Nhalf ? 1 : 0);
    int pos = atomicAdd(&cursor[key], 1);
    order[pos] = (int)(p >> BSHIFT);
  }
  __syncthreads();

  // export gapped CSR (per-node run = [nodeStart[2l], nodeStart[2l+2]))
  for (int i = tid; i < cnt; i += 512) gorder[e0 + i] = (uint)order[i];
  if (tid < BSZ) {
    const int n = b * BSZ + tid;
    if (n < N) {
      gns[n] = e0 + nodeStart[2 * tid];
      gne[n] = e0 + nodeStart[2 * tid + 2];
    }
  }

  const int nodes = min(BSZ, N - b * BSZ);
  const int g = lane >> 3, e = lane & 7;   // 8 lanes x uint2 = 64B row

  // phase 1: low-half sources
  for (int n = wid; n < nodes; n += 8) {
    const int s = nodeStart[2 * n], t = nodeStart[2 * n + 1];
    __half2 ax = __floats2half2_rn(0.f, 0.f), ay = ax;
    int j = s;
    for (; j + 16 <= t; j += 16) {
      int r0 = order[j + g], r1 = order[j + 8 + g];
      uint2 v0 = ((const uint2*)(feat + (size_t)r0 * FW))[e];
      uint2 v1 = ((const uint2*)(feat + (size_t)r1 * FW))[e];
      ax = __hadd2(ax, __hadd2(u2h(v0.x), u2h(v1.x)));
      ay = __hadd2(ay, __hadd2(u2h(v0.y), u2h(v1.y)));
    }
    for (; j < t; j += 8) {
      if (j + g < t) {
        int r = order[j + g];
        uint2 v = ((const uint2*)(feat + (size_t)r * FW))[e];
        ax = __hadd2(ax, u2h(v.x));
        ay = __hadd2(ay, u2h(v.y));
      }
    }
    #pragma unroll
    for (int m = 8; m < 64; m <<= 1) {
      ax = __hadd2(ax, u2h((uint)__shfl_xor((int)h2u(ax), m, 64)));
      ay = __hadd2(ay, u2h((uint)__shfl_xor((int)h2u(ay), m, 64)));
    }
    if (g == 0) stash[n * 8 + e] = make_uint2(h2u(ax), h2u(ay));
  }
  __syncthreads();   // phase barrier: switch L2 working set

  // phase 2: high-half sources + combine + write
  for (int n = wid; n < nodes; n += 8) {
    const int s = nodeStart[2 * n + 1], t = nodeStart[2 * n + 2];
    __half2 ax = __floats2half2_rn(0.f, 0.f), ay = ax;
    int j = s;
    for (; j + 16 <= t; j += 16) {
      int r0 = order[j + g], r1 = order[j + 8 + g];
      uint2 v0 = ((const uint2*)(feat + (size_t)r0 * FW))[e];
      uint2 v1 = ((const uint2*)(feat + (size_t)r1 * FW))[e];
      ax = __hadd2(ax, __hadd2(u2h(v0.x), u2h(v1.x)));
      ay = __hadd2(ay, __hadd2(u2h(v0.y), u2h(v1.y)));
    }
    for (; j < t; j += 8) {
      if (j + g < t) {
        int r = order[j + g];
        uint2 v = ((const uint2*)(feat + (size_t)r * FW))[e];
        ax = __hadd2(ax, u2h(v.x));
        ay = __hadd2(ay, u2h(v.y));
      }
    }
    #pragma unroll
    for (int m = 8; m < 64; m <<= 1) {
      ax = __hadd2(ax, u2h((uint)__shfl_xor((int)h2u(ax), m, 64)));
      ay = __hadd2(ay, u2h((uint)__shfl_xor((int)h2u(ay), m, 64)));
    }
    if (g == 0) {
      uint2 st = stash[n * 8 + e];
      ax = __hadd2(ax, u2h(st.x));
      ay = __hadd2(ay, u2h(st.y));
      const int deg = nodeStart[2 * n + 2] - nodeStart[2 * n];
      float inv = 1.f / fmaxf((float)deg, 1.f);
      float2 fx = __half22float2(ax), fy = __half22float2(ay);
      __half2 o0 = __floats2half2_rn(fx.x * inv, fx.y * inv);
      __half2 o1 = __floats2half2_rn(fy.x * inv, fy.y * inv);
      uint2 o = { h2u(o0), h2u(o1) };
      ((uint2*)(aggr + ((size_t)(b * BSZ + n)) * FW))[e] = o;
    }
  }
}

// ---------- fused conv1 lin + scalar head projections ----------
__global__ __launch_bounds__(256) void k_conv1fused(
    const __half* __restrict__ axm, const __half* __restrict__ xh,
    const __half* __restrict__ U1T, const __half* __restrict__ U2T,
    const float* __restrict__ c1, const float* __restrict__ svecs,
    float2* __restrict__ tsd, float2* __restrict__ ssd, int N) {
  __shared__ _Float16 tile[4][16 * HID];
  __shared__ float svec[512];    // [vs|vd|us|ud]
  const int lane = threadIdx.x & 63;
  const int wid = threadIdx.x >> 6;
  const int row0 = blockIdx.x * 64 + wid * 16;
  const int lr = lane & 15;
  const int lk = (lane >> 4) * 8;

  for (int i = threadIdx.x; i < 512; i += 256) svec[i] = svecs[i];

  {
    f16x8 b1[8], b2[8];
    #pragma unroll
    for (int ct = 0; ct < 8; ++ct) {
      const int c = ct * 16 + lr;
      b1[ct] = *(const f16x8*)((const _Float16*)U1T + (size_t)c * IN_X + lk);
      b2[ct] = *(const f16x8*)((const _Float16*)U2T + (size_t)c * IN_X + lk);
    }
    f32x4 acc[8];
    #pragma unroll
    for (int ct = 0; ct < 8; ++ct) {
      float bv = c1[ct * 16 + lr];
      acc[ct] = (f32x4){bv, bv, bv, bv};
    }
    const int rA = min(row0 + lr, N - 1);
    f16x8 a1 = *(const f16x8*)((const _Float16*)axm + (size_t)rA * IN_X + lk);
    f16x8 a2 = *(const f16x8*)((const _Float16*)xh + (size_t)rA * IN_X + lk);
    #pragma unroll
    for (int ct = 0; ct < 8; ++ct)
      acc[ct] = __builtin_amdgcn_mfma_f32_16x16x32_f16(a1, b1[ct], acc[ct], 0, 0, 0);
    #pragma unroll
    for (int ct = 0; ct < 8; ++ct)
      acc[ct] = __builtin_amdgcn_mfma_f32_16x16x32_f16(a2, b2[ct], acc[ct], 0, 0, 0);
    #pragma unroll
    for (int ct = 0; ct < 8; ++ct) {
      #pragma unroll
      for (int r = 0; r < 4; ++r) {
        const int row = (lane >> 4) * 4 + r;
        const int col = ct * 16 + lr;
        int idx = (row * HID + col) ^ ((row & 7) << 3);
        tile[wid][idx] = (_Float16)fmaxf(acc[ct][r], 0.f);
      }
    }
  }
  __syncthreads();

  // dots: lane = row (0..15) x quarter (0..3); each lane covers 32 cols
  const int row = lane & 15, q = lane >> 4;
  float ts = 0.f, td = 0.f, ss = 0.f, sd = 0.f;
  #pragma unroll
  for (int t = 0; t < 4; ++t) {
    const int col = q * 32 + t * 8;
    int idx = (row * HID + col) ^ ((row & 7) << 3);
    f16x8 h = *(const f16x8*)&tile[wid][idx];
    #pragma unroll
    for (int i = 0; i < 8; ++i) {
      float hv = (float)h[i];
      ts += hv * svec[col + i];
      td += hv * svec[128 + col + i];
      ss += hv * svec[256 + col + i];
      sd += hv * svec[384 + col + i];
    }
  }
  ts += __shfl_xor(ts, 16, 64); ts += __shfl_xor(ts, 32, 64);
  td += __shfl_xor(td, 16, 64); td += __shfl_xor(td, 32, 64);
  ss += __shfl_xor(ss, 16, 64); ss += __shfl_xor(ss, 32, 64);
  sd += __shfl_xor(sd, 16, 64); sd += __shfl_xor(sd, 32, 64);
  if (q == 0) {
    const int grow = row0 + row;
    if (grow < N) {
      tsd[grow] = make_float2(ts, td);
      ssd[grow] = make_float2(ss, sd);
    }
  }
}

// ---------- conv2 scalar aggregation: gs/gd from L2-resident 8B gathers ----
__global__ __launch_bounds__(256) void k_scalagg(const float2* __restrict__ tsd,
    const float2* __restrict__ ssd, const int* __restrict__ gns,
    const int* __restrict__ gne, const uint* __restrict__ gorder,
    const float* __restrict__ hb,
    float* __restrict__ gs, float* __restrict__ gd, int N) {
  const int n = blockIdx.x * 256 + threadIdx.x;
  if (n >= N) return;
  const int s = gns[n], t = gne[n];
  float ax = 0.f, ay = 0.f;
  int j = s;
  for (; j + 4 <= t; j += 4) {
    int r0 = (int)gorder[j],     r1 = (int)gorder[j + 1];
    int r2 = (int)gorder[j + 2], r3 = (int)gorder[j + 3];
    float2 a = tsd[r0], b = tsd[r1], c = tsd[r2], d = tsd[r3];
    ax += (a.x + b.x) + (c.x + d.x);
    ay += (a.y + b.y) + (c.y + d.y);
  }
  for (; j < t; ++j) {
    float2 a = tsd[(int)gorder[j]];
    ax += a.x; ay += a.y;
  }
  const float inv = 1.f / fmaxf((float)(t - s), 1.f);
  const float2 sv = ssd[n];
  gs[n] = sv.x + ax * inv + hb[0];
  gd[n] = sv.y + ay * inv + hb[1];
}

// ---------- per-edge: raw = gs[src] + gd[dst] + bp; sigmoid ----------
__global__ __launch_bounds__(256) void k_edge(const float* __restrict__ gs,
    const float* __restrict__ gd, const int* __restrict__ srcI,
    const int* __restrict__ dstI, const float* __restrict__ bp,
    float* __restrict__ out, int E) {
  int e = blockIdx.x * 256 + threadIdx.x;
  if (e >= E) return;
  float raw = gs[srcI[e]] + gd[dstI[e]] + bp[0];
  out[e] = raw;
  out[(size_t)E + e] = 1.f / (1.f + expf(-raw));
}

extern "C" void kernel_launch(void* const* d_in, const int* in_sizes, int n_in,
                              void* d_out, int out_size, void* d_ws, size_t ws_size,
                              hipStream_t stream) {
  const float* x   = (const float*)d_in[0];
  const int*   ei  = (const int*)d_in[1];
  const float* W0  = (const float*)d_in[2];
  const float* b0  = (const float*)d_in[3];
  const float* W1l = (const float*)d_in[4];
  const float* b1l = (const float*)d_in[5];
  const float* W1r = (const float*)d_in[6];
  const float* W2l = (const float*)d_in[7];
  const float* b2l = (const float*)d_in[8];
  const float* W2r = (const float*)d_in[9];
  const float* Wp  = (const float*)d_in[10];
  const float* bp  = (const float*)d_in[11];

  const int N = in_sizes[0] / IN_X;
  const int E = in_sizes[1] / 2;
  const int* srcI = ei;
  const int* dstI = ei + E;
  float* out = (float*)d_out;

  const int NB = (N + BSZ - 1) >> BSHIFT;
  const int nchunk = (E + CHUNK - 1) / CHUNK;

  // workspace layout
  __half* xh  = (__half*)d_ws;                   // [N][32]
  __half* axm = xh + (size_t)N * IN_X;           // [N][32]
  float2* tsd = (float2*)(axm + (size_t)N * IN_X);  // [N]
  float2* ssd = tsd + N;                         // [N]
  float* gs   = (float*)(ssd + N);               // [N]
  float* gd   = gs + N;                          // [N]
  uintptr_t wp = ((uintptr_t)(gd + N) + 15) & ~(uintptr_t)15;
  __half* U1T  = (__half*)wp;                    // [128][32]
  __half* U2T  = U1T + HID * IN_X;
  float* c1    = (float*)(U2T + HID * IN_X);     // [128]
  float* svecs = c1 + HID;                       // [512] = vs|vd|us|ud
  float* hb    = svecs + 512;                    // [2]
  int* gcursor = (int*)(hb + 2);                 // [NBP]
  int* gns     = gcursor + NBP;                  // [N+1]
  int* gne     = gns + N + 1;                    // [N]
  uint* bucketData = (uint*)(gne + N);           // [NBP*CAP]
  uint* gorder     = bucketData + (size_t)NBP * CAP;  // [NBP*CAP]

  const int xblocks = (N * IN_X / 8 + 255) / 256;
  k_prep<<<36 + xblocks, 256, 0, stream>>>(W0, b0, W1l, b1l, W1r, W2l, W2r,
                                           b2l, Wp, U1T, U2T, c1, svecs, hb,
                                           gcursor, x, xh, N * IN_X);
  // fused bucket build
  k_scatfuse<<<nchunk, 512, 0, stream>>>(srcI, dstI, gcursor, bucketData, E);
  // conv1: axm = mean(xh_j) cache-phased, counting sort + gapped CSR export
  k_baggr32s<<<NB, 512, 0, stream>>>(xh, bucketData, gcursor, axm, gorder,
                                     gns, gne, N, N / 2);
  // fused conv1 lin + scalar head projections
  k_conv1fused<<<(N + 63) / 64, 256, 0, stream>>>(axm, xh, U1T, U2T, c1,
                                                  svecs, tsd, ssd, N);
  // conv2 scalar aggregation
  k_scalagg<<<(N + 255) / 256, 256, 0, stream>>>(tsd, ssd, gns, gne, gorder,
                                                 hb, gs, gd, N);
  // edge head
  k_edge<<<(E + 255) / 256, 256, 0, stream>>>(gs, gd, srcI, dstI, bp, out, E);
}

// Round 14
// 128.678 us; speedup vs baseline: 1.7299x; 1.0016x over previous
//
#include <hip/hip_runtime.h>
#include <hip/hip_bf16.h>
#include <hip/hip_fp16.h>

// GraphSAGE fwd, round 14.
// lin0 folded into conv1 (U1=W0@W1l, U2=W0@W1r, c1=b0@(W1l+W1r)+b1l).
// Conv2 collapsed to scalars -> 8B gathers from 800KB L2-resident table.
// Bucket build: one fused kernel. Conv1 gather: cache-phased (srcHalf sort
// key) AND 4-node-interleaved per wave (32 rows in flight — R13 showed the
// L2-resident gather is latency-bound at 8 rows in flight, 43us flat).

#define IN_X 32
#define IN_E 64
#define HID 128
#define OUTF 64

#define BSHIFT 7
#define BSZ 128          // nodes per bucket
#define NBP 1024         // padded bucket count
#define CHUNK 4096       // edges per scatter block
#define CAP 4096         // slots per bucket (mean 2560, +30 sigma)

typedef _Float16 f16x8 __attribute__((ext_vector_type(8)));
typedef float f32x4 __attribute__((ext_vector_type(4)));

__device__ __forceinline__ float2 h2f2(uint v) {
  __half2 h = *reinterpret_cast<__half2*>(&v);
  return __half22float2(h);
}
__device__ __forceinline__ __half2 u2h(uint v) {
  return *reinterpret_cast<__half2*>(&v);
}
__device__ __forceinline__ uint h2u(__half2 h) {
  return *reinterpret_cast<uint*>(&h);
}

// ---------- prep: U1T/U2T, c1, head consts, svecs, zero gcursor, xh ----------
__global__ __launch_bounds__(256) void k_prep(
    const float* __restrict__ W0, const float* __restrict__ b0,
    const float* __restrict__ W1l, const float* __restrict__ b1l,
    const float* __restrict__ W1r,
    const float* __restrict__ W2l, const float* __restrict__ W2r,
    const float* __restrict__ b2l, const float* __restrict__ Wp,
    __half* __restrict__ U1T, __half* __restrict__ U2T, float* __restrict__ c1,
    float* __restrict__ svecs, float* __restrict__ hb, int* __restrict__ gcursor,
    const float* __restrict__ x, __half* __restrict__ xh, int xtotal) {
  const int blk = blockIdx.x;
  if (blk < 32) {
    __shared__ float sW0[IN_X * IN_E];
    for (int t = threadIdx.x; t < IN_X * IN_E; t += 256) sW0[t] = W0[t];
    __syncthreads();
    const int o = blk * 256 + threadIdx.x;
    const int hf = o >> 12;
    const int rem = o & 4095;
    const int j = rem >> 5, i = rem & 31;
    const float* W = hf ? W1r : W1l;
    float u = 0.f;
    #pragma unroll 8
    for (int k = 0; k < IN_E; ++k) u += sW0[i * IN_E + k] * W[k * HID + j];
    (hf ? U2T : U1T)[j * IN_X + i] = __float2half(u);
  } else if (blk == 32) {
    const int j = threadIdx.x;
    if (j < HID) {
      float cv = b1l[j];
      for (int k = 0; k < IN_E; ++k)
        cv += b0[k] * (W1l[k * HID + j] + W1r[k * HID + j]);
      c1[j] = cv;
    } else if (j == HID || j == HID + 1) {
      const float* w = Wp + (j - HID) * OUTF;
      float s = 0.f;
      for (int k = 0; k < OUTF; ++k) s += b2l[k] * w[k];
      hb[j - HID] = s;
    }
  } else if (blk == 33 || blk == 34) {
    __shared__ float sW[HID * OUTF];   // 32 KB
    const float* W = (blk == 33) ? W2l : W2r;
    for (int t = threadIdx.x; t < HID * OUTF; t += 256) sW[t] = W[t];
    __syncthreads();
    const int vec = threadIdx.x >> 7;
    const int j = threadIdx.x & 127;
    const float* w = Wp + vec * OUTF;
    float s = 0.f;
    #pragma unroll 8
    for (int k = 0; k < OUTF; ++k) s += sW[j * OUTF + k] * w[k];
    svecs[(blk - 33) * 256 + vec * 128 + j] = s;
  } else if (blk == 35) {
    #pragma unroll
    for (int k = 0; k < NBP / 256; ++k) gcursor[k * 256 + threadIdx.x] = 0;
  } else {
    int i = ((blk - 36) * 256 + threadIdx.x) * 8;
    if (i < xtotal) {
      float4 a = *(const float4*)(x + i);
      float4 b = *(const float4*)(x + i + 4);
      __half2 h0 = __floats2half2_rn(a.x, a.y);
      __half2 h1 = __floats2half2_rn(a.z, a.w);
      __half2 h2 = __floats2half2_rn(b.x, b.y);
      __half2 h3 = __floats2half2_rn(b.z, b.w);
      uint4 o = { *(uint*)&h0, *(uint*)&h1, *(uint*)&h2, *(uint*)&h3 };
      *(uint4*)(xh + i) = o;
    }
  }
}

// ---------- fused bucket build: hist -> global reserve -> scatter ----------
__global__ __launch_bounds__(512) void k_scatfuse(const int* __restrict__ src,
    const int* __restrict__ dst, int* __restrict__ gcursor,
    uint* __restrict__ bucketData, int E) {
  __shared__ int hist[NBP];
  const int cblk = blockIdx.x;
  for (int i = threadIdx.x; i < NBP; i += 512) hist[i] = 0;
  __syncthreads();
  const int base = cblk * CHUNK;
  int d[CHUNK / 512], s[CHUNK / 512];
  #pragma unroll
  for (int k = 0; k < CHUNK / 512; ++k) {
    int e = base + k * 512 + threadIdx.x;
    d[k] = (e < E) ? dst[e] : -1;
    s[k] = (e < E) ? src[e] : 0;
  }
  #pragma unroll
  for (int k = 0; k < CHUNK / 512; ++k)
    if (d[k] >= 0) atomicAdd(&hist[d[k] >> BSHIFT], 1);
  __syncthreads();
  for (int i = threadIdx.x; i < NBP; i += 512) {
    int h = hist[i];
    hist[i] = (h > 0) ? atomicAdd(&gcursor[i], h) : 0;
  }
  __syncthreads();
  #pragma unroll
  for (int k = 0; k < CHUNK / 512; ++k) {
    if (d[k] >= 0) {
      int bkt = d[k] >> BSHIFT;
      int pos = atomicAdd(&hist[bkt], 1);
      if (pos < CAP)
        bucketData[(size_t)bkt * CAP + pos] =
            ((uint)s[k] << BSHIFT) | (uint)(d[k] & (BSZ - 1));
    }
  }
}

// ---------- conv1 aggregation (cache-phased, 4-node interleave) ----------
__global__ __launch_bounds__(512) void k_baggr32s(const __half* __restrict__ feat,
    const uint* __restrict__ bucketData, const int* __restrict__ gcnt,
    __half* __restrict__ aggr, uint* __restrict__ gorder,
    int* __restrict__ gns, int* __restrict__ gne, int N, int Nhalf) {
  constexpr int FW = IN_X;     // 32 halves per row
  __shared__ int nodeStart[2 * BSZ + 1];
  __shared__ int cursor[2 * BSZ];
  __shared__ int order[CAP];
  __shared__ uint2 stash[BSZ * 8];   // 8 KB packed-fp16 partials
  const int b = blockIdx.x;
  const int tid = threadIdx.x;
  const int lane = tid & 63, wid = tid >> 6;
  const int e0 = b * CAP;
  const int cnt = min(gcnt[b], CAP);

  for (int i = tid; i < 2 * BSZ; i += 512) cursor[i] = 0;
  __syncthreads();
  for (int i = tid; i < cnt; i += 512) {
    uint p = bucketData[e0 + i];
    int key = ((p & (BSZ - 1)) << 1) | ((int)(p >> BSHIFT) >= Nhalf ? 1 : 0);
    atomicAdd(&cursor[key], 1);
  }
  __syncthreads();

  // exclusive scan over 256 counters (wave 0, 4 segments of 64 with carry)
  if (wid == 0) {
    int carry = 0;
    #pragma unroll
    for (int seg = 0; seg < 4; ++seg) {
      int v = cursor[seg * 64 + lane];
      int x = v;
      #pragma unroll
      for (int s = 1; s < 64; s <<= 1) {
        int y = __shfl_up(x, s, 64);
        if (lane >= s) x += y;
      }
      nodeStart[seg * 64 + lane] = carry + x - v;
      carry += __shfl(x, 63, 64);
    }
    if (lane == 0) nodeStart[2 * BSZ] = carry;
  }
  __syncthreads();
  for (int i = tid; i < 2 * BSZ; i += 512) cursor[i] = nodeStart[i];
  __syncthreads();

  for (int i = tid; i < cnt; i += 512) {
    uint p = bucketData[e0 + i];
    int key = ((p & (BSZ - 1)) << 1) | ((int)(p >> BSHIFT) >= Nhalf ? 1 : 0);
    int pos = atomicAdd(&cursor[key], 1);
    order[pos] = (int)(p >> BSHIFT);
  }
  __syncthreads();

  // export gapped CSR
  for (int i = tid; i < cnt; i += 512) gorder[e0 + i] = (uint)order[i];
  if (tid < BSZ) {
    const int n = b * BSZ + tid;
    if (n < N) {
      gns[n] = e0 + nodeStart[2 * tid];
      gne[n] = e0 + nodeStart[2 * tid + 2];
    }
  }

  const int nodes = min(BSZ, N - b * BSZ);
  const int g = lane >> 3, e = lane & 7;   // 8 lanes x uint2 = 64B row

  // two phases (ph=0: low-half srcs, ph=1: high-half), 4 nodes interleaved
  #pragma unroll
  for (int ph = 0; ph < 2; ++ph) {
    for (int k = 0; k < 16; k += 4) {
      const int n0 = wid + 8 * k,        n1 = wid + 8 * (k + 1);
      const int n2 = wid + 8 * (k + 2),  n3 = wid + 8 * (k + 3);
      int j0 = (n0 < nodes) ? nodeStart[2 * n0 + ph] : 0;
      int t0 = (n0 < nodes) ? nodeStart[2 * n0 + ph + 1] : 0;
      int j1 = (n1 < nodes) ? nodeStart[2 * n1 + ph] : 0;
      int t1 = (n1 < nodes) ? nodeStart[2 * n1 + ph + 1] : 0;
      int j2 = (n2 < nodes) ? nodeStart[2 * n2 + ph] : 0;
      int t2 = (n2 < nodes) ? nodeStart[2 * n2 + ph + 1] : 0;
      int j3 = (n3 < nodes) ? nodeStart[2 * n3 + ph] : 0;
      int t3 = (n3 < nodes) ? nodeStart[2 * n3 + ph + 1] : 0;
      __half2 ax0 = __floats2half2_rn(0.f, 0.f), ay0 = ax0;
      __half2 ax1 = ax0, ay1 = ax0, ax2 = ax0, ay2 = ax0, ax3 = ax0, ay3 = ax0;
      while (j0 < t0 || j1 < t1 || j2 < t2 || j3 < t3) {
        uint2 v0, v1, v2, v3;
        const bool a0 = j0 + g < t0, a1 = j1 + g < t1;
        const bool a2 = j2 + g < t2, a3 = j3 + g < t3;
        if (a0) { int r = order[j0 + g]; v0 = ((const uint2*)(feat + (size_t)r * FW))[e]; }
        if (a1) { int r = order[j1 + g]; v1 = ((const uint2*)(feat + (size_t)r * FW))[e]; }
        if (a2) { int r = order[j2 + g]; v2 = ((const uint2*)(feat + (size_t)r * FW))[e]; }
        if (a3) { int r = order[j3 + g]; v3 = ((const uint2*)(feat + (size_t)r * FW))[e]; }
        if (a0) { ax0 = __hadd2(ax0, u2h(v0.x)); ay0 = __hadd2(ay0, u2h(v0.y)); }
        if (a1) { ax1 = __hadd2(ax1, u2h(v1.x)); ay1 = __hadd2(ay1, u2h(v1.y)); }
        if (a2) { ax2 = __hadd2(ax2, u2h(v2.x)); ay2 = __hadd2(ay2, u2h(v2.y)); }
        if (a3) { ax3 = __hadd2(ax3, u2h(v3.x)); ay3 = __hadd2(ay3, u2h(v3.y)); }
        j0 += 8; j1 += 8; j2 += 8; j3 += 8;
      }
      // reduce across the 8 row-groups (m = 8,16,32)
      #pragma unroll
      for (int m = 8; m < 64; m <<= 1) {
        ax0 = __hadd2(ax0, u2h((uint)__shfl_xor((int)h2u(ax0), m, 64)));
        ay0 = __hadd2(ay0, u2h((uint)__shfl_xor((int)h2u(ay0), m, 64)));
        ax1 = __hadd2(ax1, u2h((uint)__shfl_xor((int)h2u(ax1), m, 64)));
        ay1 = __hadd2(ay1, u2h((uint)__shfl_xor((int)h2u(ay1), m, 64)));
        ax2 = __hadd2(ax2, u2h((uint)__shfl_xor((int)h2u(ax2), m, 64)));
        ay2 = __hadd2(ay2, u2h((uint)__shfl_xor((int)h2u(ay2), m, 64)));
        ax3 = __hadd2(ax3, u2h((uint)__shfl_xor((int)h2u(ax3), m, 64)));
        ay3 = __hadd2(ay3, u2h((uint)__shfl_xor((int)h2u(ay3), m, 64)));
      }
      if (g == 0) {
        if (ph == 0) {
          if (n0 < nodes) stash[n0 * 8 + e] = make_uint2(h2u(ax0), h2u(ay0));
          if (n1 < nodes) stash[n1 * 8 + e] = make_uint2(h2u(ax1), h2u(ay1));
          if (n2 < nodes) stash[n2 * 8 + e] = make_uint2(h2u(ax2), h2u(ay2));
          if (n3 < nodes) stash[n3 * 8 + e] = make_uint2(h2u(ax3), h2u(ay3));
        } else {
          if (n0 < nodes) {
            uint2 st = stash[n0 * 8 + e];
            ax0 = __hadd2(ax0, u2h(st.x)); ay0 = __hadd2(ay0, u2h(st.y));
            const int deg = nodeStart[2 * n0 + 2] - nodeStart[2 * n0];
            float inv = 1.f / fmaxf((float)deg, 1.f);
            float2 fx = __half22float2(ax0), fy = __half22float2(ay0);
            __half2 o0 = __floats2half2_rn(fx.x * inv, fx.y * inv);
            __half2 o1 = __floats2half2_rn(fy.x * inv, fy.y * inv);
            ((uint2*)(aggr + ((size_t)(b * BSZ + n0)) * FW))[e] = make_uint2(h2u(o0), h2u(o1));
          }
          if (n1 < nodes) {
            uint2 st = stash[n1 * 8 + e];
            ax1 = __hadd2(ax1, u2h(st.x)); ay1 = __hadd2(ay1, u2h(st.y));
            const int deg = nodeStart[2 * n1 + 2] - nodeStart[2 * n1];
            float inv = 1.f / fmaxf((float)deg, 1.f);
            float2 fx = __half22float2(ax1), fy = __half22float2(ay1);
            __half2 o0 = __floats2half2_rn(fx.x * inv, fx.y * inv);
            __half2 o1 = __floats2half2_rn(fy.x * inv, fy.y * inv);
            ((uint2*)(aggr + ((size_t)(b * BSZ + n1)) * FW))[e] = make_uint2(h2u(o0), h2u(o1));
          }
          if (n2 < nodes) {
            uint2 st = stash[n2 * 8 + e];
            ax2 = __hadd2(ax2, u2h(st.x)); ay2 = __hadd2(ay2, u2h(st.y));
            const int deg = nodeStart[2 * n2 + 2] - nodeStart[2 * n2];
            float inv = 1.f / fmaxf((float)deg, 1.f);
            float2 fx = __half22float2(ax2), fy = __half22float2(ay2);
            __half2 o0 = __floats2half2_rn(fx.x * inv, fx.y * inv);
            __half2 o1 = __floats2half2_rn(fy.x * inv, fy.y * inv);
            ((uint2*)(aggr + ((size_t)(b * BSZ + n2)) * FW))[e] = make_uint2(h2u(o0), h2u(o1));
          }
          if (n3 < nodes) {
            uint2 st = stash[n3 * 8 + e];
            ax3 = __hadd2(ax3, u2h(st.x)); ay3 = __hadd2(ay3, u2h(st.y));
            const int deg = nodeStart[2 * n3 + 2] - nodeStart[2 * n3];
            float inv = 1.f / fmaxf((float)deg, 1.f);
            float2 fx = __half22float2(ax3), fy = __half22float2(ay3);
            __half2 o0 = __floats2half2_rn(fx.x * inv, fx.y * inv);
            __half2 o1 = __floats2half2_rn(fy.x * inv, fy.y * inv);
            ((uint2*)(aggr + ((size_t)(b * BSZ + n3)) * FW))[e] = make_uint2(h2u(o0), h2u(o1));
          }
        }
      }
    }
    if (ph == 0) __syncthreads();   // switch L2 working set
  }
}

// ---------- fused conv1 lin + scalar head projections ----------
__global__ __launch_bounds__(256) void k_conv1fused(
    const __half* __restrict__ axm, const __half* __restrict__ xh,
    const __half* __restrict__ U1T, const __half* __restrict__ U2T,
    const float* __restrict__ c1, const float* __restrict__ svecs,
    float2* __restrict__ tsd, float2* __restrict__ ssd, int N) {
  __shared__ _Float16 tile[4][16 * HID];
  __shared__ float svec[512];    // [vs|vd|us|ud]
  const int lane = threadIdx.x & 63;
  const int wid = threadIdx.x >> 6;
  const int row0 = blockIdx.x * 64 + wid * 16;
  const int lr = lane & 15;
  const int lk = (lane >> 4) * 8;

  for (int i = threadIdx.x; i < 512; i += 256) svec[i] = svecs[i];

  {
    f16x8 b1[8], b2[8];
    #pragma unroll
    for (int ct = 0; ct < 8; ++ct) {
      const int c = ct * 16 + lr;
      b1[ct] = *(const f16x8*)((const _Float16*)U1T + (size_t)c * IN_X + lk);
      b2[ct] = *(const f16x8*)((const _Float16*)U2T + (size_t)c * IN_X + lk);
    }
    f32x4 acc[8];
    #pragma unroll
    for (int ct = 0; ct < 8; ++ct) {
      float bv = c1[ct * 16 + lr];
      acc[ct] = (f32x4){bv, bv, bv, bv};
    }
    const int rA = min(row0 + lr, N - 1);
    f16x8 a1 = *(const f16x8*)((const _Float16*)axm + (size_t)rA * IN_X + lk);
    f16x8 a2 = *(const f16x8*)((const _Float16*)xh + (size_t)rA * IN_X + lk);
    #pragma unroll
    for (int ct = 0; ct < 8; ++ct)
      acc[ct] = __builtin_amdgcn_mfma_f32_16x16x32_f16(a1, b1[ct], acc[ct], 0, 0, 0);
    #pragma unroll
    for (int ct = 0; ct < 8; ++ct)
      acc[ct] = __builtin_amdgcn_mfma_f32_16x16x32_f16(a2, b2[ct], acc[ct], 0, 0, 0);
    #pragma unroll
    for (int ct = 0; ct < 8; ++ct) {
      #pragma unroll
      for (int r = 0; r < 4; ++r) {
        const int row = (lane >> 4) * 4 + r;
        const int col = ct * 16 + lr;
        int idx = (row * HID + col) ^ ((row & 7) << 3);
        tile[wid][idx] = (_Float16)fmaxf(acc[ct][r], 0.f);
      }
    }
  }
  __syncthreads();

  const int row = lane & 15, q = lane >> 4;
  float ts = 0.f, td = 0.f, ss = 0.f, sd = 0.f;
  #pragma unroll
  for (int t = 0; t < 4; ++t) {
    const int col = q * 32 + t * 8;
    int idx = (row * HID + col) ^ ((row & 7) << 3);
    f16x8 h = *(const f16x8*)&tile[wid][idx];
    #pragma unroll
    for (int i = 0; i < 8; ++i) {
      float hv = (float)h[i];
      ts += hv * svec[col + i];
      td += hv * svec[128 + col + i];
      ss += hv * svec[256 + col + i];
      sd += hv * svec[384 + col + i];
    }
  }
  ts += __shfl_xor(ts, 16, 64); ts += __shfl_xor(ts, 32, 64);
  td += __shfl_xor(td, 16, 64); td += __shfl_xor(td, 32, 64);
  ss += __shfl_xor(ss, 16, 64); ss += __shfl_xor(ss, 32, 64);
  sd += __shfl_xor(sd, 16, 64); sd += __shfl_xor(sd, 32, 64);
  if (q == 0) {
    const int grow = row0 + row;
    if (grow < N) {
      tsd[grow] = make_float2(ts, td);
      ssd[grow] = make_float2(ss, sd);
    }
  }
}

// ---------- conv2 scalar aggregation ----------
__global__ __launch_bounds__(256) void k_scalagg(const float2* __restrict__ tsd,
    const float2* __restrict__ ssd, const int* __restrict__ gns,
    const int* __restrict__ gne, const uint* __restrict__ gorder,
    const float* __restrict__ hb,
    float* __restrict__ gs, float* __restrict__ gd, int N) {
  const int n = blockIdx.x * 256 + threadIdx.x;
  if (n >= N) return;
  const int s = gns[n], t = gne[n];
  float ax = 0.f, ay = 0.f;
  int j = s;
  for (; j + 4 <= t; j += 4) {
    int r0 = (int)gorder[j],     r1 = (int)gorder[j + 1];
    int r2 = (int)gorder[j + 2], r3 = (int)gorder[j + 3];
    float2 a = tsd[r0], b = tsd[r1], c = tsd[r2], d = tsd[r3];
    ax += (a.x + b.x) + (c.x + d.x);
    ay += (a.y + b.y) + (c.y + d.y);
  }
  for (; j < t; ++j) {
    float2 a = tsd[(int)gorder[j]];
    ax += a.x; ay += a.y;
  }
  const float inv = 1.f / fmaxf((float)(t - s), 1.f);
  const float2 sv = ssd[n];
  gs[n] = sv.x + ax * inv + hb[0];
  gd[n] = sv.y + ay * inv + hb[1];
}

// ---------- per-edge: raw = gs[src] + gd[dst] + bp; sigmoid ----------
__global__ __launch_bounds__(256) void k_edge(const float* __restrict__ gs,
    const float* __restrict__ gd, const int* __restrict__ srcI,
    const int* __restrict__ dstI, const float* __restrict__ bp,
    float* __restrict__ out, int E) {
  int e = blockIdx.x * 256 + threadIdx.x;
  if (e >= E) return;
  float raw = gs[srcI[e]] + gd[dstI[e]] + bp[0];
  out[e] = raw;
  out[(size_t)E + e] = 1.f / (1.f + expf(-raw));
}

extern "C" void kernel_launch(void* const* d_in, const int* in_sizes, int n_in,
                              void* d_out, int out_size, void* d_ws, size_t ws_size,
                              hipStream_t stream) {
  const float* x   = (const float*)d_in[0];
  const int*   ei  = (const int*)d_in[1];
  const float* W0  = (const float*)d_in[2];
  const float* b0  = (const float*)d_in[3];
  const float* W1l = (const float*)d_in[4];
  const float* b1l = (const float*)d_in[5];
  const float* W1r = (const float*)d_in[6];
  const float* W2l = (const float*)d_in[7];
  const float* b2l = (const float*)d_in[8];
  const float* W2r = (const float*)d_in[9];
  const float* Wp  = (const float*)d_in[10];
  const float* bp  = (const float*)d_in[11];

  const int N = in_sizes[0] / IN_X;
  const int E = in_sizes[1] / 2;
  const int* srcI = ei;
  const int* dstI = ei + E;
  float* out = (float*)d_out;

  const int NB = (N + BSZ - 1) >> BSHIFT;
  const int nchunk = (E + CHUNK - 1) / CHUNK;

  // workspace layout
  __half* xh  = (__half*)d_ws;                   // [N][32]
  __half* axm = xh + (size_t)N * IN_X;           // [N][32]
  float2* tsd = (float2*)(axm + (size_t)N * IN_X);  // [N]
  float2* ssd = tsd + N;                         // [N]
  float* gs   = (float*)(ssd + N);               // [N]
  float* gd   = gs + N;                          // [N]
  uintptr_t wp = ((uintptr_t)(gd + N) + 15) & ~(uintptr_t)15;
  __half* U1T  = (__half*)wp;                    // [128][32]
  __half* U2T  = U1T + HID * IN_X;
  float* c1    = (float*)(U2T + HID * IN_X);     // [128]
  float* svecs = c1 + HID;                       // [512] = vs|vd|us|ud
  float* hb    = svecs + 512;                    // [2]
  int* gcursor = (int*)(hb + 2);                 // [NBP]
  int* gns     = gcursor + NBP;                  // [N+1]
  int* gne     = gns + N + 1;                    // [N]
  uint* bucketData = (uint*)(gne + N);           // [NBP*CAP]
  uint* gorder     = bucketData + (size_t)NBP * CAP;  // [NBP*CAP]

  const int xblocks = (N * IN_X / 8 + 255) / 256;
  k_prep<<<36 + xblocks, 256, 0, stream>>>(W0, b0, W1l, b1l, W1r, W2l, W2r,
                                           b2l, Wp, U1T, U2T, c1, svecs, hb,
                                           gcursor, x, xh, N * IN_X);
  // fused bucket build
  k_scatfuse<<<nchunk, 512, 0, stream>>>(srcI, dstI, gcursor, bucketData, E);
  // conv1: axm = mean(xh_j) cache-phased + 4-node interleave
  k_baggr32s<<<NB, 512, 0, stream>>>(xh, bucketData, gcursor, axm, gorder,
                                     gns, gne, N, N / 2);
  // fused conv1 lin + scalar head projections
  k_conv1fused<<<(N + 63) / 64, 256, 0, stream>>>(axm, xh, U1T, U2T, c1,
                                                  svecs, tsd, ssd, N);
  // conv2 scalar aggregation
  k_scalagg<<<(N + 255) / 256, 256, 0, stream>>>(tsd, ssd, gns, gne, gorder,
                                                 hb, gs, gd, N);
  // edge head
  k_edge<<<(E + 255) / 256, 256, 0, stream>>>(gs, gd, srcI, dstI, bp, out, E);
}